// Round 4
// baseline (705.821 us; speedup 1.0000x reference)
//
#include <hip/hip_runtime.h>
#include <hip/hip_bf16.h>
#include <math.h>

// GPT-small fwd: B=2, T=1024, D=512, H=8, HD=64, L=2, V=50257
// bf16 MFMA (16x16x32) for all matmuls, fp32 residual/LN/softmax/loss.

typedef short bf16x8 __attribute__((ext_vector_type(8)));
typedef float f32x4 __attribute__((ext_vector_type(4)));

#define NTOK   2048
#define DMODEL 512
#define TSEQ   1024
#define NVOC   50257
#define VPAD   50304
#define NPART  786        // 393 col-tiles * 2 wave-halves

// ---------------------------------------------------------------- helpers
__device__ __forceinline__ float gelu_exact(float x) {
    return 0.5f * x * (1.f + erff(x * 0.70710678118654752f));
}
__device__ __forceinline__ float bf2f(short s) {
    unsigned u = ((unsigned)(unsigned short)s) << 16;
    union { unsigned u; float f; } c; c.u = u; return c.f;
}

typedef __attribute__((address_space(1))) const void global_cvoid;
typedef __attribute__((address_space(3))) void lds_void;
__device__ __forceinline__ void glds16(const void* g, void* l) {
    // async global->LDS, 16B/lane; LDS dest = wave-uniform base + lane*16
    __builtin_amdgcn_global_load_lds((global_cvoid*)g, (lds_void*)l, 16, 0, 0);
}

// ---------------------------------------------------------------- f32 -> bf16 (zero-pad past nsrc4)
__global__ __launch_bounds__(256) void conv_bf16(const float* __restrict__ in,
                                                 __hip_bfloat16* __restrict__ out,
                                                 long n4, long nsrc4) {
    for (long i = (long)blockIdx.x * blockDim.x + threadIdx.x; i < n4;
         i += (long)gridDim.x * blockDim.x) {
        float4 v;
        if (i < nsrc4) v = ((const float4*)in)[i];
        else { v.x = v.y = v.z = v.w = 0.f; }
        alignas(8) __hip_bfloat16 t[4];
        t[0] = __float2bfloat16(v.x); t[1] = __float2bfloat16(v.y);
        t[2] = __float2bfloat16(v.z); t[3] = __float2bfloat16(v.w);
        *(uint2*)&out[i * 4] = *(uint2*)t;
    }
}

// ---------------------------------------------------------------- embedding
__global__ __launch_bounds__(128) void embed_k(const int* __restrict__ idx,
                                               const float* __restrict__ tok,
                                               const float* __restrict__ pos,
                                               float* __restrict__ x) {
    int row = blockIdx.x;
    int t = row & (TSEQ - 1);
    int id = idx[row];
    const float4* a = (const float4*)(tok + (long)id * DMODEL);
    const float4* p = (const float4*)(pos + (long)t * DMODEL);
    float4* o = (float4*)(x + (long)row * DMODEL);
    int i = threadIdx.x;
    float4 u = a[i], q = p[i];
    u.x += q.x; u.y += q.y; u.z += q.z; u.w += q.w;
    o[i] = u;
}

// ---------------------------------------------------------------- LayerNorm (wave per row), fp32 -> bf16
__global__ __launch_bounds__(256) void ln_rows(const float* __restrict__ x,
                                               const float* __restrict__ w,
                                               const float* __restrict__ b,
                                               __hip_bfloat16* __restrict__ out,
                                               int nrows) {
    int wv = threadIdx.x >> 6, l = threadIdx.x & 63;
    int row = blockIdx.x * 4 + wv;
    if (row >= nrows) return;
    const float4* xr = (const float4*)(x + (long)row * DMODEL);
    float4 v0 = xr[l * 2], v1 = xr[l * 2 + 1];
    float s = v0.x + v0.y + v0.z + v0.w + v1.x + v1.y + v1.z + v1.w;
    for (int o = 32; o; o >>= 1) s += __shfl_xor(s, o);
    float mu = s * (1.f / DMODEL);
    float d, q = 0.f;
    d = v0.x - mu; q += d * d; d = v0.y - mu; q += d * d;
    d = v0.z - mu; q += d * d; d = v0.w - mu; q += d * d;
    d = v1.x - mu; q += d * d; d = v1.y - mu; q += d * d;
    d = v1.z - mu; q += d * d; d = v1.w - mu; q += d * d;
    for (int o = 32; o; o >>= 1) q += __shfl_xor(q, o);
    float rs = rsqrtf(q * (1.f / DMODEL) + 1e-5f);
    const float4* wr = (const float4*)w; const float4* br = (const float4*)b;
    float4 w0 = wr[l * 2], w1 = wr[l * 2 + 1], b0 = br[l * 2], b1 = br[l * 2 + 1];
    alignas(16) __hip_bfloat16 t[8];
    t[0] = __float2bfloat16((v0.x - mu) * rs * w0.x + b0.x);
    t[1] = __float2bfloat16((v0.y - mu) * rs * w0.y + b0.y);
    t[2] = __float2bfloat16((v0.z - mu) * rs * w0.z + b0.z);
    t[3] = __float2bfloat16((v0.w - mu) * rs * w0.w + b0.w);
    t[4] = __float2bfloat16((v1.x - mu) * rs * w1.x + b1.x);
    t[5] = __float2bfloat16((v1.y - mu) * rs * w1.y + b1.y);
    t[6] = __float2bfloat16((v1.z - mu) * rs * w1.z + b1.z);
    t[7] = __float2bfloat16((v1.w - mu) * rs * w1.w + b1.w);
    *(int4*)&out[(long)row * DMODEL + l * 8] = *(int4*)t;
}

// ---------------------------------------------------------------- GEMM: C = alpha * A(MxK) * B(NxK)^T [+bias][gelu][+resid]
// 2-phase double-buffered K-loop (T3 minimal): stage tile t+1 BEFORE computing
// tile t, single vmcnt(0)+barrier per tile (compiler-emitted at __syncthreads).
// Fragment-linear LDS: chunk = 16 rows x 32 k; lane l stages (row=l&15,
// k=(l>>4)*8) so a wave's ds_read_b128 at l*16B is a contiguous conflict-free
// 1KB burst with compile-time chunk offsets. BK=32 fixed.
template<int BM, int BN, int WM, int WN, bool OBF16, bool BIAS, bool GELUF,
         bool RESID, bool SWZ, bool LSE>
__global__ __launch_bounds__(256) void gemm_bt(
    const __hip_bfloat16* __restrict__ A, int lda, long sAhi, long sAlo,
    const __hip_bfloat16* __restrict__ B, int ldb, long sBhi, long sBlo,
    void* __restrict__ Cp, long ldc, long sChi, long sClo,
    const float* __restrict__ bias,
    int K, int Nc, float alpha, int zdiv, float2* __restrict__ lsePart) {
    static_assert(WM * WN == 4, "4 waves");
    constexpr int BK = 32;
    constexpr int FM = BM / (WM * 16), FN = BN / (WN * 16);
    constexpr int CAW = (BM / 16) / 4, CBW = (BN / 16) / 4;  // chunks per wave
    __shared__ __align__(16) __hip_bfloat16 lsA0[BM * BK], lsA1[BM * BK];
    __shared__ __align__(16) __hip_bfloat16 lsB0[BN * BK], lsB1[BN * BK];
    const int tid = threadIdx.x;
    const int l = tid & 63, w = tid >> 6;
    const int wr = w / WN, wc = w % WN;
    int bx = blockIdx.x, by = blockIdx.y;
    if (SWZ) {  // bijective chunked XCD swizzle (grid total % 8 == 0)
        int lin = by * gridDim.x + bx;
        int q = (gridDim.x * gridDim.y) >> 3;
        int nl = (lin & 7) * q + (lin >> 3);
        bx = nl % gridDim.x; by = nl / gridDim.x;
    }
    const int z = blockIdx.z;
    const int zh = z / zdiv, zl = z % zdiv;
    const __hip_bfloat16* Az = A + (long)zh * sAhi + (long)zl * sAlo;
    const __hip_bfloat16* Bz = B + (long)zh * sBhi + (long)zl * sBlo;
    const long Coff = (long)zh * sChi + (long)zl * sClo;
    const int m0 = bx * BM, n0 = by * BN;
    const int lr = l & 15, lk = l >> 4;

    // per-lane staging source pointers, advanced by BK per stage
    const __hip_bfloat16* pA[CAW];
    const __hip_bfloat16* pB[CBW];
#pragma unroll
    for (int i = 0; i < CAW; ++i)
        pA[i] = Az + (long)(m0 + (w * CAW + i) * 16 + lr) * lda + lk * 8;
#pragma unroll
    for (int i = 0; i < CBW; ++i)
        pB[i] = Bz + (long)(n0 + (w * CBW + i) * 16 + lr) * ldb + lk * 8;

    f32x4 acc[FM][FN];
#pragma unroll
    for (int m = 0; m < FM; ++m)
#pragma unroll
        for (int n = 0; n < FN; ++n)
            for (int r = 0; r < 4; ++r) acc[m][n][r] = 0.f;

    auto stage = [&](__hip_bfloat16* dA, __hip_bfloat16* dB) {
#pragma unroll
        for (int i = 0; i < CAW; ++i) {
            glds16(pA[i], dA + (w * CAW + i) * 512);
            pA[i] += BK;
        }
#pragma unroll
        for (int i = 0; i < CBW; ++i) {
            glds16(pB[i], dB + (w * CBW + i) * 512);
            pB[i] += BK;
        }
    };
    auto compute = [&](const __hip_bfloat16* bA, const __hip_bfloat16* bB) {
        bf16x8 af[FM], bv[FN];
#pragma unroll
        for (int m = 0; m < FM; ++m)
            af[m] = *(const bf16x8*)&bA[(wr * FM + m) * 512 + l * 8];
#pragma unroll
        for (int n = 0; n < FN; ++n)
            bv[n] = *(const bf16x8*)&bB[(wc * FN + n) * 512 + l * 8];
#pragma unroll
        for (int m = 0; m < FM; ++m)
#pragma unroll
            for (int n = 0; n < FN; ++n)
                acc[m][n] = __builtin_amdgcn_mfma_f32_16x16x32_bf16(
                    af[m], bv[n], acc[m][n], 0, 0, 0);
    };

    // prologue: stage tile 0
    stage(lsA0, lsB0);
    __syncthreads();
    const int nt = K / BK;   // even, >= 2 at all call sites
    for (int t = 0; t < nt - 2; t += 2) {
        stage(lsA1, lsB1);       // issue t+1 loads (in flight during compute)
        compute(lsA0, lsB0);
        __syncthreads();         // drains vmcnt(0): t+1 tile ready
        stage(lsA0, lsB0);       // issue t+2
        compute(lsA1, lsB1);
        __syncthreads();
    }
    stage(lsA1, lsB1);           // last tile
    compute(lsA0, lsB0);
    __syncthreads();
    compute(lsA1, lsB1);

#pragma unroll
    for (int m = 0; m < FM; ++m) {
        int rowb = m0 + wr * FM * 16 + m * 16 + lk * 4;
#pragma unroll
        for (int n = 0; n < FN; ++n) {
            int col = n0 + wc * FN * 16 + n * 16 + lr;
            if (col < Nc) {
#pragma unroll
                for (int r = 0; r < 4; ++r) {
                    float v = acc[m][n][r] * alpha;
                    if (BIAS) v += bias[col];
                    if (GELUF) v = gelu_exact(v);
                    long cidx = Coff + (long)(rowb + r) * ldc + col;
                    if (OBF16) {
                        ((__hip_bfloat16*)Cp)[cidx] = __float2bfloat16(v);
                    } else {
                        float* Cf = (float*)Cp;
                        if (RESID) v += Cf[cidx];
                        Cf[cidx] = v;
                    }
                }
            }
        }
    }

    if constexpr (LSE) {  // per-(row, 64-col half) partial logsumexp from acc
        int pcol = by * WN + wc;
#pragma unroll
        for (int m = 0; m < FM; ++m) {
#pragma unroll
            for (int r = 0; r < 4; ++r) {
                float mx = -INFINITY;
#pragma unroll
                for (int n = 0; n < FN; ++n) {
                    int col = n0 + wc * FN * 16 + n * 16 + lr;
                    if (col < Nc) mx = fmaxf(mx, acc[m][n][r]);
                }
                mx = fmaxf(mx, __shfl_xor(mx, 1, 16));
                mx = fmaxf(mx, __shfl_xor(mx, 2, 16));
                mx = fmaxf(mx, __shfl_xor(mx, 4, 16));
                mx = fmaxf(mx, __shfl_xor(mx, 8, 16));
                float s = 0.f;
#pragma unroll
                for (int n = 0; n < FN; ++n) {
                    int col = n0 + wc * FN * 16 + n * 16 + lr;
                    if (col < Nc) s += __expf(acc[m][n][r] - mx);
                }
                s += __shfl_xor(s, 1, 16); s += __shfl_xor(s, 2, 16);
                s += __shfl_xor(s, 4, 16); s += __shfl_xor(s, 8, 16);
                if (lr == 0) {
                    int row = m0 + wr * FM * 16 + m * 16 + lk * 4 + r;
                    lsePart[(long)row * NPART + pcol] = make_float2(mx, s);
                }
            }
        }
    }
}

// ---------------------------------------------------------------- causal softmax, one pass in registers
__global__ __launch_bounds__(256) void att_softmax(__hip_bfloat16* __restrict__ P) {
    int q = blockIdx.x, z = blockIdx.y;
    __hip_bfloat16* row = P + (long)z * (TSEQ * TSEQ) + (long)q * TSEQ;
    int len = q + 1;
    int tid = threadIdx.x;
    short4 v = *(const short4*)&row[tid * 4];
    float x[4];
#pragma unroll
    for (int j = 0; j < 4; ++j) {
        int k = tid * 4 + j;
        short sv = (&v.x)[j];
        x[j] = (k < len) ? bf2f(sv) : -INFINITY;
    }
    __shared__ float red[8];
    float m = fmaxf(fmaxf(x[0], x[1]), fmaxf(x[2], x[3]));
    for (int o = 32; o; o >>= 1) m = fmaxf(m, __shfl_xor(m, o));
    if ((tid & 63) == 0) red[tid >> 6] = m;
    __syncthreads();
    m = fmaxf(fmaxf(red[0], red[1]), fmaxf(red[2], red[3]));
    float e[4];
    float s = 0.f;
#pragma unroll
    for (int j = 0; j < 4; ++j) {
        e[j] = (x[j] == -INFINITY) ? 0.f : __expf(x[j] - m);
        s += e[j];
    }
    for (int o = 32; o; o >>= 1) s += __shfl_xor(s, o);
    if ((tid & 63) == 0) red[4 + (tid >> 6)] = s;
    __syncthreads();
    s = red[4] + red[5] + red[6] + red[7];
    float inv = 1.f / s;
    alignas(8) __hip_bfloat16 t[4];
#pragma unroll
    for (int j = 0; j < 4; ++j) t[j] = __float2bfloat16(e[j] * inv);
    *(short4*)&row[tid * 4] = *(short4*)t;
}

// ---------------------------------------------------------------- V transpose: vT[z][64][1024]
__global__ __launch_bounds__(256) void vtrans(const __hip_bfloat16* __restrict__ qkv,
                                              __hip_bfloat16* __restrict__ vT) {
    int z = blockIdx.y; int b = z >> 3, h = z & 7;
    int k0 = blockIdx.x * 64;
    __shared__ __hip_bfloat16 t[64 * 65];
    int tid = threadIdx.x;
#pragma unroll
    for (int i = 0; i < 16; ++i) {
        int lin = i * 256 + tid;
        int k = lin >> 6, n = lin & 63;
        t[k * 65 + n] =
            qkv[(long)(b * TSEQ + k0 + k) * 1536 + 1024 + h * 64 + n];
    }
    __syncthreads();
#pragma unroll
    for (int i = 0; i < 16; ++i) {
        int lin = i * 256 + tid;
        int n = lin >> 6, k = lin & 63;
        vT[(long)z * (64 * TSEQ) + (long)n * TSEQ + k0 + k] = t[k * 65 + n];
    }
}

// ---------------------------------------------------------------- merge per-row LSE partials -> nll
__global__ __launch_bounds__(256) void nll_part(const float2* __restrict__ part,
                                                const float* __restrict__ logits,
                                                const int* __restrict__ tgt,
                                                float* __restrict__ nll) {
    int row = blockIdx.x;
    const float2* p = part + (long)row * NPART;
    __shared__ float sm[4], ss[4];
    float m = -INFINITY, s = 0.f;
    for (int i = threadIdx.x; i < NPART; i += 256) {
        float2 v = p[i];
        float M = fmaxf(m, v.x);
        s = s * __expf(m - M) + v.y * __expf(v.x - M);
        m = M;
    }
    for (int o = 32; o; o >>= 1) {
        float om = __shfl_xor(m, o), os = __shfl_xor(s, o);
        float M = fmaxf(m, om);
        s = s * __expf(m - M) + os * __expf(om - M);
        m = M;
    }
    if ((threadIdx.x & 63) == 0) { sm[threadIdx.x >> 6] = m; ss[threadIdx.x >> 6] = s; }
    __syncthreads();
    if (threadIdx.x == 0) {
        float M = fmaxf(fmaxf(sm[0], sm[1]), fmaxf(sm[2], sm[3]));
        float S = ss[0] * expf(sm[0] - M) + ss[1] * expf(sm[1] - M) +
                  ss[2] * expf(sm[2] - M) + ss[3] * expf(sm[3] - M);
        nll[row] = M + logf(S) - logits[(long)row * NVOC + tgt[row]];
    }
}

__global__ __launch_bounds__(256) void loss_final(const float* __restrict__ nll,
                                                  float* __restrict__ out) {
    __shared__ float red[4];
    float s = 0.f;
    for (int i = threadIdx.x; i < NTOK; i += 256) s += nll[i];
    for (int o = 32; o; o >>= 1) s += __shfl_xor(s, o);
    if ((threadIdx.x & 63) == 0) red[threadIdx.x >> 6] = s;
    __syncthreads();
    if (threadIdx.x == 0)
        out[0] = (red[0] + red[1] + red[2] + red[3]) * (1.f / NTOK);
}

// ---------------------------------------------------------------- launch
extern "C" void kernel_launch(void* const* d_in, const int* in_sizes, int n_in,
                              void* d_out, int out_size, void* d_ws, size_t ws_size,
                              hipStream_t stream) {
    (void)in_sizes; (void)n_in; (void)out_size;
    const int*   idx  = (const int*)d_in[0];
    const int*   tgt  = (const int*)d_in[1];
    const float* tok  = (const float*)d_in[2];
    const float* pos  = (const float*)d_in[3];
    const float* ln1w = (const float*)d_in[4];
    const float* ln1b = (const float*)d_in[5];
    const float* attw = (const float*)d_in[6];
    const float* attb = (const float*)d_in[7];
    const float* prjw = (const float*)d_in[8];
    const float* prjb = (const float*)d_in[9];
    const float* ln2w = (const float*)d_in[10];
    const float* ln2b = (const float*)d_in[11];
    const float* fcw  = (const float*)d_in[12];
    const float* fcb  = (const float*)d_in[13];
    const float* fc2w = (const float*)d_in[14];
    const float* fc2b = (const float*)d_in[15];
    const float* lnfw = (const float*)d_in[16];
    const float* lnfb = (const float*)d_in[17];
    float* dof = (float*)d_out;

    char* base = (char*)d_ws;
    long off = 0;
    float* xf = (float*)(base + off);           off += (long)NTOK * DMODEL * 4;
    __hip_bfloat16* hbf  = (__hip_bfloat16*)(base + off); off += (long)NTOK * DMODEL * 2;
    __hip_bfloat16* qkvb = (__hip_bfloat16*)(base + off); off += (long)NTOK * 1536 * 2;
    __hip_bfloat16* Pb   = (__hip_bfloat16*)(base + off); off += 16L * TSEQ * TSEQ * 2;
    __hip_bfloat16* vTb  = (__hip_bfloat16*)(base + off); off += 16L * 64 * TSEQ * 2;
    __hip_bfloat16* ybf  = (__hip_bfloat16*)(base + off); off += (long)NTOK * DMODEL * 2;
    __hip_bfloat16* fc1b = (__hip_bfloat16*)(base + off); off += (long)NTOK * 2048 * 2;
    __hip_bfloat16* wAtt = (__hip_bfloat16*)(base + off); off += 2L * 1536 * 512 * 2;
    __hip_bfloat16* wPrj = (__hip_bfloat16*)(base + off); off += 2L * 512 * 512 * 2;
    __hip_bfloat16* wFc  = (__hip_bfloat16*)(base + off); off += 2L * 2048 * 512 * 2;
    __hip_bfloat16* wFc2 = (__hip_bfloat16*)(base + off); off += 2L * 512 * 2048 * 2;
    __hip_bfloat16* tokB = (__hip_bfloat16*)(base + off); off += (long)VPAD * DMODEL * 2;
    float2* lseP = (float2*)(base + off);       off += (long)NTOK * NPART * 8;
    float* nllb = (float*)(base + off);         off += NTOK * 4;
    if ((size_t)off > ws_size) return;

    {
        long n4;
        n4 = 2L * 1536 * 512 / 4;
        conv_bf16<<<dim3(1536), 256, 0, stream>>>(attw, wAtt, n4, n4);
        n4 = 2L * 512 * 512 / 4;
        conv_bf16<<<dim3(512), 256, 0, stream>>>(prjw, wPrj, n4, n4);
        n4 = 2L * 2048 * 512 / 4;
        conv_bf16<<<dim3(2048), 256, 0, stream>>>(fcw, wFc, n4, n4);
        n4 = 2L * 512 * 2048 / 4;
        conv_bf16<<<dim3(2048), 256, 0, stream>>>(fc2w, wFc2, n4, n4);
        long t4 = (long)VPAD * DMODEL / 4, s4 = (long)NVOC * DMODEL / 4;
        conv_bf16<<<dim3(4096), 256, 0, stream>>>(tok, tokB, t4, s4);
    }

    embed_k<<<dim3(NTOK), 128, 0, stream>>>(idx, tok, pos, xf);

    for (int l = 0; l < 2; ++l) {
        ln_rows<<<dim3(512), 256, 0, stream>>>(xf, ln1w + l * 512, ln1b + l * 512, hbf, NTOK);
        // QKV: [2048,512] x [1536,512]^T -> bf16 + bias   (384 blocks)
        gemm_bt<128, 64, 2, 2, true, true, false, false, false, false>
            <<<dim3(16, 24, 1), 256, 0, stream>>>(
            hbf, 512, 0, 0, wAtt + (long)l * 1536 * 512, 512, 0, 0,
            qkvb, 1536, 0, 0, attb + l * 1536, 512, 1536, 1.f, 1, nullptr);
        // S = Q K^T / 8 (batched z=16)
        gemm_bt<128, 128, 2, 2, true, false, false, false, false, false>
            <<<dim3(8, 8, 16), 256, 0, stream>>>(
            qkvb, 1536, 1536L * TSEQ, 64, qkvb + 512, 1536, 1536L * TSEQ, 64,
            Pb, TSEQ, 8L * TSEQ * TSEQ, (long)TSEQ * TSEQ, nullptr,
            64, TSEQ, 0.125f, 8, nullptr);
        att_softmax<<<dim3(TSEQ, 16), 256, 0, stream>>>(Pb);
        vtrans<<<dim3(16, 16), 256, 0, stream>>>(qkvb, vTb);
        // y = P V  (256 blocks)
        gemm_bt<64, 64, 2, 2, true, false, false, false, false, false>
            <<<dim3(16, 1, 16), 256, 0, stream>>>(
            Pb, TSEQ, 8L * TSEQ * TSEQ, (long)TSEQ * TSEQ,
            vTb, TSEQ, 8L * 64 * TSEQ, 64L * TSEQ,
            ybf, 512, 512L * TSEQ, 64, nullptr, TSEQ, 64, 1.f, 8, nullptr);
        // x += y W_proj^T + b  (256 blocks)
        gemm_bt<64, 64, 2, 2, false, true, false, true, false, false>
            <<<dim3(32, 8, 1), 256, 0, stream>>>(
            ybf, 512, 0, 0, wPrj + (long)l * 512 * 512, 512, 0, 0,
            xf, 512, 0, 0, prjb + l * 512, 512, 512, 1.f, 1, nullptr);
        ln_rows<<<dim3(512), 256, 0, stream>>>(xf, ln2w + l * 512, ln2b + l * 512, hbf, NTOK);
        // fc1 + gelu  (256 blocks)
        gemm_bt<128, 128, 2, 2, true, true, true, false, false, false>
            <<<dim3(16, 16, 1), 256, 0, stream>>>(
            hbf, 512, 0, 0, wFc + (long)l * 2048 * 512, 512, 0, 0,
            fc1b, 2048, 0, 0, fcb + l * 2048, 512, 2048, 1.f, 1, nullptr);
        // x += fc1 W_fc2^T + b  (256 blocks)
        gemm_bt<64, 64, 2, 2, false, true, false, true, false, false>
            <<<dim3(32, 8, 1), 256, 0, stream>>>(
            fc1b, 2048, 0, 0, wFc2 + (long)l * 512 * 2048, 2048, 0, 0,
            xf, 512, 0, 0, fc2b + l * 512, 2048, 512, 1.f, 1, nullptr);
    }

    ln_rows<<<dim3(512), 256, 0, stream>>>(xf, lnfw, lnfb, hbf, NTOK);
    // logits + fused partial-LSE (6288 blocks, XCD-swizzled)
    gemm_bt<128, 128, 2, 2, false, false, false, false, true, true>
        <<<dim3(16, 393, 1), 256, 0, stream>>>(
        hbf, 512, 0, 0, tokB, 512, 0, 0,
        dof, NVOC, 0, 0, nullptr, 512, NVOC, 1.f, 1, lseP);

    nll_part<<<dim3(NTOK), 256, 0, stream>>>(lseP, dof, tgt, nllb);
    loss_final<<<dim3(1), 256, 0, stream>>>(nllb, dof + (long)NTOK * NVOC);
}

// Round 5
// 656.117 us; speedup vs baseline: 1.0758x; 1.0758x over previous
//
#include <hip/hip_runtime.h>
#include <hip/hip_bf16.h>
#include <math.h>

// GPT-small fwd: B=2, T=1024, D=512, H=8, HD=64, L=2, V=50257
// bf16 MFMA (16x16x32) for all matmuls, fp32 residual/LN/softmax/loss.

typedef short bf16x8 __attribute__((ext_vector_type(8)));
typedef float f32x4 __attribute__((ext_vector_type(4)));

#define NTOK   2048
#define DMODEL 512
#define TSEQ   1024
#define NVOC   50257
#define VPAD   50304
#define NPART  786        // 393 col-tiles * 2 wave-halves

// ---------------------------------------------------------------- helpers
__device__ __forceinline__ float gelu_exact(float x) {
    return 0.5f * x * (1.f + erff(x * 0.70710678118654752f));
}
__device__ __forceinline__ float bf2f(short s) {
    unsigned u = ((unsigned)(unsigned short)s) << 16;
    union { unsigned u; float f; } c; c.u = u; return c.f;
}

typedef __attribute__((address_space(1))) const void global_cvoid;
typedef __attribute__((address_space(3))) void lds_void;
__device__ __forceinline__ void glds16(const void* g, void* l) {
    // async global->LDS, 16B/lane; LDS dest = wave-uniform base + lane*16
    __builtin_amdgcn_global_load_lds((global_cvoid*)g, (lds_void*)l, 16, 0, 0);
}

// ---------------------------------------------------------------- f32 -> bf16 (zero-pad past nsrc4)
__global__ __launch_bounds__(256) void conv_bf16(const float* __restrict__ in,
                                                 __hip_bfloat16* __restrict__ out,
                                                 long n4, long nsrc4) {
    for (long i = (long)blockIdx.x * blockDim.x + threadIdx.x; i < n4;
         i += (long)gridDim.x * blockDim.x) {
        float4 v;
        if (i < nsrc4) v = ((const float4*)in)[i];
        else { v.x = v.y = v.z = v.w = 0.f; }
        alignas(8) __hip_bfloat16 t[4];
        t[0] = __float2bfloat16(v.x); t[1] = __float2bfloat16(v.y);
        t[2] = __float2bfloat16(v.z); t[3] = __float2bfloat16(v.w);
        *(uint2*)&out[i * 4] = *(uint2*)t;
    }
}

// ---------------------------------------------------------------- embedding
__global__ __launch_bounds__(128) void embed_k(const int* __restrict__ idx,
                                               const float* __restrict__ tok,
                                               const float* __restrict__ pos,
                                               float* __restrict__ x) {
    int row = blockIdx.x;
    int t = row & (TSEQ - 1);
    int id = idx[row];
    const float4* a = (const float4*)(tok + (long)id * DMODEL);
    const float4* p = (const float4*)(pos + (long)t * DMODEL);
    float4* o = (float4*)(x + (long)row * DMODEL);
    int i = threadIdx.x;
    float4 u = a[i], q = p[i];
    u.x += q.x; u.y += q.y; u.z += q.z; u.w += q.w;
    o[i] = u;
}

// ---------------------------------------------------------------- LayerNorm (wave per row), fp32 -> bf16
__global__ __launch_bounds__(256) void ln_rows(const float* __restrict__ x,
                                               const float* __restrict__ w,
                                               const float* __restrict__ b,
                                               __hip_bfloat16* __restrict__ out,
                                               int nrows) {
    int wv = threadIdx.x >> 6, l = threadIdx.x & 63;
    int row = blockIdx.x * 4 + wv;
    if (row >= nrows) return;
    const float4* xr = (const float4*)(x + (long)row * DMODEL);
    float4 v0 = xr[l * 2], v1 = xr[l * 2 + 1];
    float s = v0.x + v0.y + v0.z + v0.w + v1.x + v1.y + v1.z + v1.w;
    for (int o = 32; o; o >>= 1) s += __shfl_xor(s, o);
    float mu = s * (1.f / DMODEL);
    float d, q = 0.f;
    d = v0.x - mu; q += d * d; d = v0.y - mu; q += d * d;
    d = v0.z - mu; q += d * d; d = v0.w - mu; q += d * d;
    d = v1.x - mu; q += d * d; d = v1.y - mu; q += d * d;
    d = v1.z - mu; q += d * d; d = v1.w - mu; q += d * d;
    for (int o = 32; o; o >>= 1) q += __shfl_xor(q, o);
    float rs = rsqrtf(q * (1.f / DMODEL) + 1e-5f);
    const float4* wr = (const float4*)w; const float4* br = (const float4*)b;
    float4 w0 = wr[l * 2], w1 = wr[l * 2 + 1], b0 = br[l * 2], b1 = br[l * 2 + 1];
    alignas(16) __hip_bfloat16 t[8];
    t[0] = __float2bfloat16((v0.x - mu) * rs * w0.x + b0.x);
    t[1] = __float2bfloat16((v0.y - mu) * rs * w0.y + b0.y);
    t[2] = __float2bfloat16((v0.z - mu) * rs * w0.z + b0.z);
    t[3] = __float2bfloat16((v0.w - mu) * rs * w0.w + b0.w);
    t[4] = __float2bfloat16((v1.x - mu) * rs * w1.x + b1.x);
    t[5] = __float2bfloat16((v1.y - mu) * rs * w1.y + b1.y);
    t[6] = __float2bfloat16((v1.z - mu) * rs * w1.z + b1.z);
    t[7] = __float2bfloat16((v1.w - mu) * rs * w1.w + b1.w);
    *(int4*)&out[(long)row * DMODEL + l * 8] = *(int4*)t;
}

// ---------------------------------------------------------------- GEMM: C = alpha * A(MxK) * B(NxK)^T [+bias][gelu][+resid]
// Single-buffer BK=32 (16-24KB LDS -> high occupancy; TLP hides the barrier
// drain, per r2-vs-r3/r4 evidence). Fragment-linear LDS: chunk = 16 rows x
// 32 k; lane l stages (row=l&15, k=(l>>4)*8) so each wave ds_read_b128 is a
// contiguous conflict-free 1KB burst at compile-time chunk offsets.
// WM*WN waves (4 -> 256 thr, 8 -> 512 thr).
template<int BM, int BN, int WM, int WN, bool OBF16, bool BIAS, bool GELUF,
         bool RESID, bool SWZ, bool LSE>
__global__ __launch_bounds__(WM * WN * 64) void gemm_bt(
    const __hip_bfloat16* __restrict__ A, int lda, long sAhi, long sAlo,
    const __hip_bfloat16* __restrict__ B, int ldb, long sBhi, long sBlo,
    void* __restrict__ Cp, long ldc, long sChi, long sClo,
    const float* __restrict__ bias,
    int K, int Nc, float alpha, int zdiv, float2* __restrict__ lsePart) {
    constexpr int NW = WM * WN;
    constexpr int FM = BM / (WM * 16), FN = BN / (WN * 16);
    constexpr int CAW = (BM / 16) / NW, CBW = (BN / 16) / NW;  // chunks/wave
    static_assert(CAW >= 1 && CBW >= 1 && (BM / 16) % NW == 0 &&
                  (BN / 16) % NW == 0, "chunk split");
    __shared__ __align__(16) __hip_bfloat16 lsA[BM * 32];
    __shared__ __align__(16) __hip_bfloat16 lsB[BN * 32];
    const int tid = threadIdx.x;
    const int l = tid & 63, w = tid >> 6;
    const int wr = w / WN, wc = w % WN;
    int bx = blockIdx.x, by = blockIdx.y;
    if (SWZ) {  // bijective chunked XCD swizzle (grid total % 8 == 0)
        int lin = by * gridDim.x + bx;
        int q = (gridDim.x * gridDim.y) >> 3;
        int nl = (lin & 7) * q + (lin >> 3);
        bx = nl % gridDim.x; by = nl / gridDim.x;
    }
    const int z = blockIdx.z;
    const int zh = z / zdiv, zl = z % zdiv;
    const __hip_bfloat16* Az = A + (long)zh * sAhi + (long)zl * sAlo;
    const __hip_bfloat16* Bz = B + (long)zh * sBhi + (long)zl * sBlo;
    const long Coff = (long)zh * sChi + (long)zl * sClo;
    const int m0 = bx * BM, n0 = by * BN;
    const int lr = l & 15, lk = l >> 4;

    // per-lane staging source pointers, advanced by 32 per K-tile
    const __hip_bfloat16* pA[CAW];
    const __hip_bfloat16* pB[CBW];
#pragma unroll
    for (int i = 0; i < CAW; ++i)
        pA[i] = Az + (long)(m0 + (w * CAW + i) * 16 + lr) * lda + lk * 8;
#pragma unroll
    for (int i = 0; i < CBW; ++i)
        pB[i] = Bz + (long)(n0 + (w * CBW + i) * 16 + lr) * ldb + lk * 8;

    f32x4 acc[FM][FN];
#pragma unroll
    for (int m = 0; m < FM; ++m)
#pragma unroll
        for (int n = 0; n < FN; ++n)
            for (int r = 0; r < 4; ++r) acc[m][n][r] = 0.f;

    const int nt = K / 32;
    for (int t = 0; t < nt; ++t) {
        __syncthreads();   // previous tile's readers done
#pragma unroll
        for (int i = 0; i < CAW; ++i) {
            glds16(pA[i], lsA + (w * CAW + i) * 512);
            pA[i] += 32;
        }
#pragma unroll
        for (int i = 0; i < CBW; ++i) {
            glds16(pB[i], lsB + (w * CBW + i) * 512);
            pB[i] += 32;
        }
        __syncthreads();   // loads drained (vmcnt 0 at barrier)
        bf16x8 af[FM], bv[FN];
#pragma unroll
        for (int m = 0; m < FM; ++m)
            af[m] = *(const bf16x8*)&lsA[(wr * FM + m) * 512 + l * 8];
#pragma unroll
        for (int n = 0; n < FN; ++n)
            bv[n] = *(const bf16x8*)&lsB[(wc * FN + n) * 512 + l * 8];
#pragma unroll
        for (int m = 0; m < FM; ++m)
#pragma unroll
            for (int n = 0; n < FN; ++n)
                acc[m][n] = __builtin_amdgcn_mfma_f32_16x16x32_bf16(
                    af[m], bv[n], acc[m][n], 0, 0, 0);
    }

#pragma unroll
    for (int m = 0; m < FM; ++m) {
        int rowb = m0 + wr * FM * 16 + m * 16 + lk * 4;
#pragma unroll
        for (int n = 0; n < FN; ++n) {
            int col = n0 + wc * FN * 16 + n * 16 + lr;
            if (col < Nc) {
#pragma unroll
                for (int r = 0; r < 4; ++r) {
                    float v = acc[m][n][r] * alpha;
                    if (BIAS) v += bias[col];
                    if (GELUF) v = gelu_exact(v);
                    long cidx = Coff + (long)(rowb + r) * ldc + col;
                    if (OBF16) {
                        ((__hip_bfloat16*)Cp)[cidx] = __float2bfloat16(v);
                    } else {
                        float* Cf = (float*)Cp;
                        if (RESID) v += Cf[cidx];
                        Cf[cidx] = v;
                    }
                }
            }
        }
    }

    if constexpr (LSE) {  // per-(row, 64-col slice) partial logsumexp from acc
        int pcol = by * WN + wc;
#pragma unroll
        for (int m = 0; m < FM; ++m) {
#pragma unroll
            for (int r = 0; r < 4; ++r) {
                float mx = -INFINITY;
#pragma unroll
                for (int n = 0; n < FN; ++n) {
                    int col = n0 + wc * FN * 16 + n * 16 + lr;
                    if (col < Nc) mx = fmaxf(mx, acc[m][n][r]);
                }
                mx = fmaxf(mx, __shfl_xor(mx, 1, 16));
                mx = fmaxf(mx, __shfl_xor(mx, 2, 16));
                mx = fmaxf(mx, __shfl_xor(mx, 4, 16));
                mx = fmaxf(mx, __shfl_xor(mx, 8, 16));
                float s = 0.f;
#pragma unroll
                for (int n = 0; n < FN; ++n) {
                    int col = n0 + wc * FN * 16 + n * 16 + lr;
                    if (col < Nc) s += __expf(acc[m][n][r] - mx);
                }
                s += __shfl_xor(s, 1, 16); s += __shfl_xor(s, 2, 16);
                s += __shfl_xor(s, 4, 16); s += __shfl_xor(s, 8, 16);
                if (lr == 0) {
                    int row = m0 + wr * FM * 16 + m * 16 + lk * 4 + r;
                    lsePart[(long)row * NPART + pcol] = make_float2(mx, s);
                }
            }
        }
    }
}

// ---------------------------------------------------------------- causal softmax, one pass in registers
__global__ __launch_bounds__(256) void att_softmax(__hip_bfloat16* __restrict__ P) {
    int q = blockIdx.x, z = blockIdx.y;
    __hip_bfloat16* row = P + (long)z * (TSEQ * TSEQ) + (long)q * TSEQ;
    int len = q + 1;
    int tid = threadIdx.x;
    short4 v = *(const short4*)&row[tid * 4];
    float x[4];
#pragma unroll
    for (int j = 0; j < 4; ++j) {
        int k = tid * 4 + j;
        short sv = (&v.x)[j];
        x[j] = (k < len) ? bf2f(sv) : -INFINITY;
    }
    __shared__ float red[8];
    float m = fmaxf(fmaxf(x[0], x[1]), fmaxf(x[2], x[3]));
    for (int o = 32; o; o >>= 1) m = fmaxf(m, __shfl_xor(m, o));
    if ((tid & 63) == 0) red[tid >> 6] = m;
    __syncthreads();
    m = fmaxf(fmaxf(red[0], red[1]), fmaxf(red[2], red[3]));
    float e[4];
    float s = 0.f;
#pragma unroll
    for (int j = 0; j < 4; ++j) {
        e[j] = (x[j] == -INFINITY) ? 0.f : __expf(x[j] - m);
        s += e[j];
    }
    for (int o = 32; o; o >>= 1) s += __shfl_xor(s, o);
    if ((tid & 63) == 0) red[4 + (tid >> 6)] = s;
    __syncthreads();
    s = red[4] + red[5] + red[6] + red[7];
    float inv = 1.f / s;
    alignas(8) __hip_bfloat16 t[4];
#pragma unroll
    for (int j = 0; j < 4; ++j) t[j] = __float2bfloat16(e[j] * inv);
    *(short4*)&row[tid * 4] = *(short4*)t;
}

// ---------------------------------------------------------------- V transpose: vT[z][64][1024]
__global__ __launch_bounds__(256) void vtrans(const __hip_bfloat16* __restrict__ qkv,
                                              __hip_bfloat16* __restrict__ vT) {
    int z = blockIdx.y; int b = z >> 3, h = z & 7;
    int k0 = blockIdx.x * 64;
    __shared__ __hip_bfloat16 t[64 * 65];
    int tid = threadIdx.x;
#pragma unroll
    for (int i = 0; i < 16; ++i) {
        int lin = i * 256 + tid;
        int k = lin >> 6, n = lin & 63;
        t[k * 65 + n] =
            qkv[(long)(b * TSEQ + k0 + k) * 1536 + 1024 + h * 64 + n];
    }
    __syncthreads();
#pragma unroll
    for (int i = 0; i < 16; ++i) {
        int lin = i * 256 + tid;
        int n = lin >> 6, k = lin & 63;
        vT[(long)z * (64 * TSEQ) + (long)n * TSEQ + k0 + k] = t[k * 65 + n];
    }
}

// ---------------------------------------------------------------- merge per-row LSE partials -> nll
__global__ __launch_bounds__(256) void nll_part(const float2* __restrict__ part,
                                                const float* __restrict__ logits,
                                                const int* __restrict__ tgt,
                                                float* __restrict__ nll) {
    int row = blockIdx.x;
    const float2* p = part + (long)row * NPART;
    __shared__ float sm[4], ss[4];
    float m = -INFINITY, s = 0.f;
    for (int i = threadIdx.x; i < NPART; i += 256) {
        float2 v = p[i];
        float M = fmaxf(m, v.x);
        s = s * __expf(m - M) + v.y * __expf(v.x - M);
        m = M;
    }
    for (int o = 32; o; o >>= 1) {
        float om = __shfl_xor(m, o), os = __shfl_xor(s, o);
        float M = fmaxf(m, om);
        s = s * __expf(m - M) + os * __expf(om - M);
        m = M;
    }
    if ((threadIdx.x & 63) == 0) { sm[threadIdx.x >> 6] = m; ss[threadIdx.x >> 6] = s; }
    __syncthreads();
    if (threadIdx.x == 0) {
        float M = fmaxf(fmaxf(sm[0], sm[1]), fmaxf(sm[2], sm[3]));
        float S = ss[0] * expf(sm[0] - M) + ss[1] * expf(sm[1] - M) +
                  ss[2] * expf(sm[2] - M) + ss[3] * expf(sm[3] - M);
        nll[row] = M + logf(S) - logits[(long)row * NVOC + tgt[row]];
    }
}

__global__ __launch_bounds__(256) void loss_final(const float* __restrict__ nll,
                                                  float* __restrict__ out) {
    __shared__ float red[4];
    float s = 0.f;
    for (int i = threadIdx.x; i < NTOK; i += 256) s += nll[i];
    for (int o = 32; o; o >>= 1) s += __shfl_xor(s, o);
    if ((threadIdx.x & 63) == 0) red[threadIdx.x >> 6] = s;
    __syncthreads();
    if (threadIdx.x == 0)
        out[0] = (red[0] + red[1] + red[2] + red[3]) * (1.f / NTOK);
}

// ---------------------------------------------------------------- launch
extern "C" void kernel_launch(void* const* d_in, const int* in_sizes, int n_in,
                              void* d_out, int out_size, void* d_ws, size_t ws_size,
                              hipStream_t stream) {
    (void)in_sizes; (void)n_in; (void)out_size;
    const int*   idx  = (const int*)d_in[0];
    const int*   tgt  = (const int*)d_in[1];
    const float* tok  = (const float*)d_in[2];
    const float* pos  = (const float*)d_in[3];
    const float* ln1w = (const float*)d_in[4];
    const float* ln1b = (const float*)d_in[5];
    const float* attw = (const float*)d_in[6];
    const float* attb = (const float*)d_in[7];
    const float* prjw = (const float*)d_in[8];
    const float* prjb = (const float*)d_in[9];
    const float* ln2w = (const float*)d_in[10];
    const float* ln2b = (const float*)d_in[11];
    const float* fcw  = (const float*)d_in[12];
    const float* fcb  = (const float*)d_in[13];
    const float* fc2w = (const float*)d_in[14];
    const float* fc2b = (const float*)d_in[15];
    const float* lnfw = (const float*)d_in[16];
    const float* lnfb = (const float*)d_in[17];
    float* dof = (float*)d_out;

    char* base = (char*)d_ws;
    long off = 0;
    float* xf = (float*)(base + off);           off += (long)NTOK * DMODEL * 4;
    __hip_bfloat16* hbf  = (__hip_bfloat16*)(base + off); off += (long)NTOK * DMODEL * 2;
    __hip_bfloat16* qkvb = (__hip_bfloat16*)(base + off); off += (long)NTOK * 1536 * 2;
    __hip_bfloat16* Pb   = (__hip_bfloat16*)(base + off); off += 16L * TSEQ * TSEQ * 2;
    __hip_bfloat16* vTb  = (__hip_bfloat16*)(base + off); off += 16L * 64 * TSEQ * 2;
    __hip_bfloat16* ybf  = (__hip_bfloat16*)(base + off); off += (long)NTOK * DMODEL * 2;
    __hip_bfloat16* fc1b = (__hip_bfloat16*)(base + off); off += (long)NTOK * 2048 * 2;
    __hip_bfloat16* wAtt = (__hip_bfloat16*)(base + off); off += 2L * 1536 * 512 * 2;
    __hip_bfloat16* wPrj = (__hip_bfloat16*)(base + off); off += 2L * 512 * 512 * 2;
    __hip_bfloat16* wFc  = (__hip_bfloat16*)(base + off); off += 2L * 2048 * 512 * 2;
    __hip_bfloat16* wFc2 = (__hip_bfloat16*)(base + off); off += 2L * 512 * 2048 * 2;
    __hip_bfloat16* tokB = (__hip_bfloat16*)(base + off); off += (long)VPAD * DMODEL * 2;
    float2* lseP = (float2*)(base + off);       off += (long)NTOK * NPART * 8;
    float* nllb = (float*)(base + off);         off += NTOK * 4;
    if ((size_t)off > ws_size) return;

    {
        long n4;
        n4 = 2L * 1536 * 512 / 4;
        conv_bf16<<<dim3(1536), 256, 0, stream>>>(attw, wAtt, n4, n4);
        n4 = 2L * 512 * 512 / 4;
        conv_bf16<<<dim3(512), 256, 0, stream>>>(prjw, wPrj, n4, n4);
        n4 = 2L * 2048 * 512 / 4;
        conv_bf16<<<dim3(2048), 256, 0, stream>>>(fcw, wFc, n4, n4);
        n4 = 2L * 512 * 2048 / 4;
        conv_bf16<<<dim3(2048), 256, 0, stream>>>(fc2w, wFc2, n4, n4);
        long t4 = (long)VPAD * DMODEL / 4, s4 = (long)NVOC * DMODEL / 4;
        conv_bf16<<<dim3(4096), 256, 0, stream>>>(tok, tokB, t4, s4);
    }

    embed_k<<<dim3(NTOK), 128, 0, stream>>>(idx, tok, pos, xf);

    for (int l = 0; l < 2; ++l) {
        ln_rows<<<dim3(512), 256, 0, stream>>>(xf, ln1w + l * 512, ln1b + l * 512, hbf, NTOK);
        // QKV: [2048,512] x [1536,512]^T -> bf16 + bias   (384 blocks)
        gemm_bt<128, 64, 2, 2, true, true, false, false, false, false>
            <<<dim3(16, 24, 1), 256, 0, stream>>>(
            hbf, 512, 0, 0, wAtt + (long)l * 1536 * 512, 512, 0, 0,
            qkvb, 1536, 0, 0, attb + l * 1536, 512, 1536, 1.f, 1, nullptr);
        // S = Q K^T / 8 (batched z=16)
        gemm_bt<128, 128, 2, 2, true, false, false, false, false, false>
            <<<dim3(8, 8, 16), 256, 0, stream>>>(
            qkvb, 1536, 1536L * TSEQ, 64, qkvb + 512, 1536, 1536L * TSEQ, 64,
            Pb, TSEQ, 8L * TSEQ * TSEQ, (long)TSEQ * TSEQ, nullptr,
            64, TSEQ, 0.125f, 8, nullptr);
        att_softmax<<<dim3(TSEQ, 16), 256, 0, stream>>>(Pb);
        vtrans<<<dim3(16, 16), 256, 0, stream>>>(qkvb, vTb);
        // y = P V  (256 blocks)
        gemm_bt<64, 64, 2, 2, true, false, false, false, false, false>
            <<<dim3(16, 1, 16), 256, 0, stream>>>(
            Pb, TSEQ, 8L * TSEQ * TSEQ, (long)TSEQ * TSEQ,
            vTb, TSEQ, 8L * 64 * TSEQ, 64L * TSEQ,
            ybf, 512, 512L * TSEQ, 64, nullptr, TSEQ, 64, 1.f, 8, nullptr);
        // x += y W_proj^T + b  (256 blocks)
        gemm_bt<64, 64, 2, 2, false, true, false, true, false, false>
            <<<dim3(32, 8, 1), 256, 0, stream>>>(
            ybf, 512, 0, 0, wPrj + (long)l * 512 * 512, 512, 0, 0,
            xf, 512, 0, 0, prjb + l * 512, 512, 512, 1.f, 1, nullptr);
        ln_rows<<<dim3(512), 256, 0, stream>>>(xf, ln2w + l * 512, ln2b + l * 512, hbf, NTOK);
        // fc1 + gelu  (256 blocks)
        gemm_bt<128, 128, 2, 2, true, true, true, false, false, false>
            <<<dim3(16, 16, 1), 256, 0, stream>>>(
            hbf, 512, 0, 0, wFc + (long)l * 2048 * 512, 512, 0, 0,
            fc1b, 2048, 0, 0, fcb + l * 2048, 512, 2048, 1.f, 1, nullptr);
        // x += fc1 W_fc2^T + b  (256 blocks)
        gemm_bt<64, 64, 2, 2, false, true, false, true, false, false>
            <<<dim3(32, 8, 1), 256, 0, stream>>>(
            fc1b, 2048, 0, 0, wFc2 + (long)l * 512 * 2048, 2048, 0, 0,
            xf, 512, 0, 0, fc2b + l * 512, 2048, 512, 1.f, 1, nullptr);
    }

    ln_rows<<<dim3(512), 256, 0, stream>>>(xf, lnfw, lnfb, hbf, NTOK);
    // logits + fused partial-LSE: 256x128 tile, 8 waves (3144 blocks, swizzled)
    gemm_bt<256, 128, 4, 2, false, false, false, false, true, true>
        <<<dim3(8, 393, 1), 512, 0, stream>>>(
        hbf, 512, 0, 0, tokB, 512, 0, 0,
        dof, NVOC, 0, 0, nullptr, 512, NVOC, 1.f, 1, lseP);

    nll_part<<<dim3(NTOK), 256, 0, stream>>>(lseP, dof, tgt, nllb);
    loss_final<<<dim3(1), 256, 0, stream>>>(nllb, dof + (long)NTOK * NVOC);
}

// Round 6
// 643.087 us; speedup vs baseline: 1.0976x; 1.0203x over previous
//
#include <hip/hip_runtime.h>
#include <hip/hip_bf16.h>
#include <math.h>

// GPT-small fwd: B=2, T=1024, D=512, H=8, HD=64, L=2, V=50257
// bf16 MFMA (16x16x32) for all matmuls, fp32 residual/LN/softmax/loss.

typedef short bf16x8 __attribute__((ext_vector_type(8)));
typedef short short8 __attribute__((ext_vector_type(8)));
typedef float f32x4 __attribute__((ext_vector_type(4)));

#define NTOK   2048
#define DMODEL 512
#define TSEQ   1024
#define NVOC   50257
#define VPAD   50304
#define NPART  786        // 393 col-tiles * 2 wave-halves

// ---------------------------------------------------------------- helpers
__device__ __forceinline__ float gelu_exact(float x) {
    return 0.5f * x * (1.f + erff(x * 0.70710678118654752f));
}
__device__ __forceinline__ float bf2f(short s) {
    unsigned u = ((unsigned)(unsigned short)s) << 16;
    union { unsigned u; float f; } c; c.u = u; return c.f;
}

typedef __attribute__((address_space(1))) const void global_cvoid;
typedef __attribute__((address_space(3))) void lds_void;
__device__ __forceinline__ void glds16(const void* g, void* l) {
    // async global->LDS, 16B/lane; LDS dest = wave-uniform base + lane*16
    __builtin_amdgcn_global_load_lds((global_cvoid*)g, (lds_void*)l, 16, 0, 0);
}
__device__ __forceinline__ void rawbar() {
    asm volatile("" ::: "memory");
    __builtin_amdgcn_s_barrier();
    asm volatile("" ::: "memory");
}

// ---------------------------------------------------------------- f32 -> bf16 (zero-pad past nsrc4)
__global__ __launch_bounds__(256) void conv_bf16(const float* __restrict__ in,
                                                 __hip_bfloat16* __restrict__ out,
                                                 long n4, long nsrc4) {
    for (long i = (long)blockIdx.x * blockDim.x + threadIdx.x; i < n4;
         i += (long)gridDim.x * blockDim.x) {
        float4 v;
        if (i < nsrc4) v = ((const float4*)in)[i];
        else { v.x = v.y = v.z = v.w = 0.f; }
        alignas(8) __hip_bfloat16 t[4];
        t[0] = __float2bfloat16(v.x); t[1] = __float2bfloat16(v.y);
        t[2] = __float2bfloat16(v.z); t[3] = __float2bfloat16(v.w);
        *(uint2*)&out[i * 4] = *(uint2*)t;
    }
}

// ---------------------------------------------------------------- embedding
__global__ __launch_bounds__(128) void embed_k(const int* __restrict__ idx,
                                               const float* __restrict__ tok,
                                               const float* __restrict__ pos,
                                               float* __restrict__ x) {
    int row = blockIdx.x;
    int t = row & (TSEQ - 1);
    int id = idx[row];
    const float4* a = (const float4*)(tok + (long)id * DMODEL);
    const float4* p = (const float4*)(pos + (long)t * DMODEL);
    float4* o = (float4*)(x + (long)row * DMODEL);
    int i = threadIdx.x;
    float4 u = a[i], q = p[i];
    u.x += q.x; u.y += q.y; u.z += q.z; u.w += q.w;
    o[i] = u;
}

// ---------------------------------------------------------------- LayerNorm (wave per row), fp32 -> bf16
__global__ __launch_bounds__(256) void ln_rows(const float* __restrict__ x,
                                               const float* __restrict__ w,
                                               const float* __restrict__ b,
                                               __hip_bfloat16* __restrict__ out,
                                               int nrows) {
    int wv = threadIdx.x >> 6, l = threadIdx.x & 63;
    int row = blockIdx.x * 4 + wv;
    if (row >= nrows) return;
    const float4* xr = (const float4*)(x + (long)row * DMODEL);
    float4 v0 = xr[l * 2], v1 = xr[l * 2 + 1];
    float s = v0.x + v0.y + v0.z + v0.w + v1.x + v1.y + v1.z + v1.w;
    for (int o = 32; o; o >>= 1) s += __shfl_xor(s, o);
    float mu = s * (1.f / DMODEL);
    float d, q = 0.f;
    d = v0.x - mu; q += d * d; d = v0.y - mu; q += d * d;
    d = v0.z - mu; q += d * d; d = v0.w - mu; q += d * d;
    d = v1.x - mu; q += d * d; d = v1.y - mu; q += d * d;
    d = v1.z - mu; q += d * d; d = v1.w - mu; q += d * d;
    for (int o = 32; o; o >>= 1) q += __shfl_xor(q, o);
    float rs = rsqrtf(q * (1.f / DMODEL) + 1e-5f);
    const float4* wr = (const float4*)w; const float4* br = (const float4*)b;
    float4 w0 = wr[l * 2], w1 = wr[l * 2 + 1], b0 = br[l * 2], b1 = br[l * 2 + 1];
    alignas(16) __hip_bfloat16 t[8];
    t[0] = __float2bfloat16((v0.x - mu) * rs * w0.x + b0.x);
    t[1] = __float2bfloat16((v0.y - mu) * rs * w0.y + b0.y);
    t[2] = __float2bfloat16((v0.z - mu) * rs * w0.z + b0.z);
    t[3] = __float2bfloat16((v0.w - mu) * rs * w0.w + b0.w);
    t[4] = __float2bfloat16((v1.x - mu) * rs * w1.x + b1.x);
    t[5] = __float2bfloat16((v1.y - mu) * rs * w1.y + b1.y);
    t[6] = __float2bfloat16((v1.z - mu) * rs * w1.z + b1.z);
    t[7] = __float2bfloat16((v1.w - mu) * rs * w1.w + b1.w);
    *(int4*)&out[(long)row * DMODEL + l * 8] = *(int4*)t;
}

// ---------------------------------------------------------------- GEMM: C = alpha * A(MxK) * B(NxK)^T [+bias][gelu][+resid]
// Counted-vmcnt double-buffered K-loop (T4): stage(next) -> vmcnt(NL) ->
// s_barrier -> compute(cur) -> s_barrier. Prefetch loads stay in flight
// across barriers (never drained to 0 in the main loop).
// Fragment-linear LDS (conflict-free ds_read_b128 bursts).
// Epilogue (non-resid): acc -> LDS bounce -> coalesced float4/short8 stores.
template<int BM, int BN, int WM, int WN, bool OBF16, bool BIAS, bool GELUF,
         bool RESID, bool SWZ, bool LSE>
__global__ __launch_bounds__(WM * WN * 64) void gemm_bt(
    const __hip_bfloat16* __restrict__ A, int lda, long sAhi, long sAlo,
    const __hip_bfloat16* __restrict__ B, int ldb, long sBhi, long sBlo,
    void* __restrict__ Cp, long ldc, long sChi, long sClo,
    const float* __restrict__ bias,
    int K, int Nc, float alpha, int zdiv, float2* __restrict__ lsePart) {
    constexpr int NW = WM * WN, NT = NW * 64;
    constexpr int FM = BM / (WM * 16), FN = BN / (WN * 16);
    constexpr int CAW = (BM / 16) / NW, CBW = (BN / 16) / NW;  // chunks/wave
    constexpr int NL = CAW + CBW;        // glds per wave per stage
    static_assert(CAW >= 1 && CBW >= 1 && (BM / 16) % NW == 0 &&
                  (BN / 16) % NW == 0, "chunk split");
    constexpr int STG = (BM + BN) * 32;  // bf16 elems per stage buffer
    constexpr int EPB = WM * 16 * BN * 4;
    constexpr int SMB = (2 * STG * 2 > EPB) ? 2 * STG * 2 : EPB;
    __shared__ __align__(16) char smem[SMB];
    __hip_bfloat16* st0 = (__hip_bfloat16*)smem;
    __hip_bfloat16* st1 = st0 + STG;
    const int tid = threadIdx.x;
    const int l = tid & 63, w = tid >> 6;
    const int wr = w / WN, wc = w % WN;
    int bx = blockIdx.x, by = blockIdx.y;
    if (SWZ) {  // bijective chunked XCD swizzle (grid total % 8 == 0)
        int lin = by * gridDim.x + bx;
        int q = (gridDim.x * gridDim.y) >> 3;
        int nl = (lin & 7) * q + (lin >> 3);
        bx = nl % gridDim.x; by = nl / gridDim.x;
    }
    const int z = blockIdx.z;
    const int zh = z / zdiv, zl = z % zdiv;
    const __hip_bfloat16* Az = A + (long)zh * sAhi + (long)zl * sAlo;
    const __hip_bfloat16* Bz = B + (long)zh * sBhi + (long)zl * sBlo;
    const long Coff = (long)zh * sChi + (long)zl * sClo;
    const int m0 = bx * BM, n0 = by * BN;
    const int lr = l & 15, lk = l >> 4;

    // per-lane staging source pointers, advanced by 32 per K-tile
    const __hip_bfloat16* pA[CAW];
    const __hip_bfloat16* pB[CBW];
#pragma unroll
    for (int i = 0; i < CAW; ++i)
        pA[i] = Az + (long)(m0 + (w * CAW + i) * 16 + lr) * lda + lk * 8;
#pragma unroll
    for (int i = 0; i < CBW; ++i)
        pB[i] = Bz + (long)(n0 + (w * CBW + i) * 16 + lr) * ldb + lk * 8;

    f32x4 acc[FM][FN];
#pragma unroll
    for (int m = 0; m < FM; ++m)
#pragma unroll
        for (int n = 0; n < FN; ++n)
            for (int r = 0; r < 4; ++r) acc[m][n][r] = 0.f;

    auto stage = [&](__hip_bfloat16* buf) {
#pragma unroll
        for (int i = 0; i < CAW; ++i) {
            glds16(pA[i], buf + (w * CAW + i) * 512);
            pA[i] += 32;
        }
#pragma unroll
        for (int i = 0; i < CBW; ++i) {
            glds16(pB[i], buf + BM * 32 + (w * CBW + i) * 512);
            pB[i] += 32;
        }
    };
    auto compute = [&](const __hip_bfloat16* buf) {
        const __hip_bfloat16* bA = buf;
        const __hip_bfloat16* bB = buf + BM * 32;
        bf16x8 af[FM], bv[FN];
#pragma unroll
        for (int m = 0; m < FM; ++m)
            af[m] = *(const bf16x8*)&bA[(wr * FM + m) * 512 + l * 8];
#pragma unroll
        for (int n = 0; n < FN; ++n)
            bv[n] = *(const bf16x8*)&bB[(wc * FN + n) * 512 + l * 8];
        __builtin_amdgcn_s_setprio(1);
#pragma unroll
        for (int m = 0; m < FM; ++m)
#pragma unroll
            for (int n = 0; n < FN; ++n)
                acc[m][n] = __builtin_amdgcn_mfma_f32_16x16x32_bf16(
                    af[m], bv[n], acc[m][n], 0, 0, 0);
        __builtin_amdgcn_s_setprio(0);
    };

    const int nt = K / 32;   // >= 2, even at all call sites
    stage(st0);
    int t = 0;
    for (; t + 2 <= nt - 1; t += 2) {
        stage(st1);
        asm volatile("s_waitcnt vmcnt(%0)" :: "n"(NL) : "memory");
        rawbar();
        compute(st0);
        rawbar();
        stage(st0);
        asm volatile("s_waitcnt vmcnt(%0)" :: "n"(NL) : "memory");
        rawbar();
        compute(st1);
        rawbar();
    }
    if (t < nt - 1) {   // nt even: one staged iter left, tail in st1
        stage(st1);
        asm volatile("s_waitcnt vmcnt(%0)" :: "n"(NL) : "memory");
        rawbar();
        compute(st0);
        rawbar();
        asm volatile("s_waitcnt vmcnt(0)" ::: "memory");
        rawbar();
        compute(st1);
    } else {            // nt odd (unused at current sites)
        asm volatile("s_waitcnt vmcnt(0)" ::: "memory");
        rawbar();
        compute(st0);
    }

    __syncthreads();   // full drain before smem reuse / epilogue

    if constexpr (!RESID) {
        // vectorized store via LDS bounce (full tiles in M; bf16 sites full in N)
        constexpr int EROW = 16 * BN;
        if constexpr (OBF16) {
            __hip_bfloat16* ep = (__hip_bfloat16*)smem;
            constexpr int VE = (WM * EROW) / (NT * 8);
#pragma unroll
            for (int mi = 0; mi < FM; ++mi) {
#pragma unroll
                for (int n = 0; n < FN; ++n) {
                    int cb = wc * FN * 16 + n * 16 + lr;
#pragma unroll
                    for (int r = 0; r < 4; ++r) {
                        float v = acc[mi][n][r] * alpha;
                        if (BIAS) v += bias[n0 + cb];
                        if (GELUF) v = gelu_exact(v);
                        ep[(wr * 16 + lk * 4 + r) * BN + cb] = __float2bfloat16(v);
                    }
                }
                __syncthreads();
#pragma unroll
                for (int i = 0; i < VE; ++i) {
                    int flat = (i * NT + tid) * 8;
                    int s = flat / EROW;
                    int rr = (flat % EROW) / BN;
                    int c = flat % BN;
                    long grow = m0 + s * FM * 16 + mi * 16 + rr;
                    *(short8*)((__hip_bfloat16*)Cp + Coff + grow * ldc + n0 + c) =
                        *(const short8*)(ep + flat);
                }
                __syncthreads();
            }
        } else {
            float* ep = (float*)smem;
            float* Cf = (float*)Cp;
            constexpr int VE = (WM * EROW) / (NT * 4);
#pragma unroll
            for (int mi = 0; mi < FM; ++mi) {
#pragma unroll
                for (int n = 0; n < FN; ++n) {
                    int cb = wc * FN * 16 + n * 16 + lr;
#pragma unroll
                    for (int r = 0; r < 4; ++r) {
                        float v = acc[mi][n][r] * alpha;
                        if (BIAS) v += bias[n0 + cb];
                        if (GELUF) v = gelu_exact(v);
                        ep[(wr * 16 + lk * 4 + r) * BN + cb] = v;
                    }
                }
                __syncthreads();
#pragma unroll
                for (int i = 0; i < VE; ++i) {
                    int flat = (i * NT + tid) * 4;
                    int s = flat / EROW;
                    int rr = (flat % EROW) / BN;
                    int c = flat % BN;
                    long grow = m0 + s * FM * 16 + mi * 16 + rr;
                    int gcol = n0 + c;
                    if (gcol + 4 <= Nc) {
                        *(float4*)(Cf + Coff + grow * ldc + gcol) =
                            *(const float4*)(ep + flat);
                    } else {
#pragma unroll
                        for (int e = 0; e < 4; ++e)
                            if (gcol + e < Nc)
                                Cf[Coff + grow * ldc + gcol + e] = ep[flat + e];
                    }
                }
                __syncthreads();
            }
        }
    } else {
        // scattered epilogue with residual read-modify-write (small GEMMs only)
#pragma unroll
        for (int m = 0; m < FM; ++m) {
            int rowb = m0 + wr * FM * 16 + m * 16 + lk * 4;
#pragma unroll
            for (int n = 0; n < FN; ++n) {
                int col = n0 + wc * FN * 16 + n * 16 + lr;
                if (col < Nc) {
#pragma unroll
                    for (int r = 0; r < 4; ++r) {
                        float v = acc[m][n][r] * alpha;
                        if (BIAS) v += bias[col];
                        if (GELUF) v = gelu_exact(v);
                        long cidx = Coff + (long)(rowb + r) * ldc + col;
                        float* Cf = (float*)Cp;
                        v += Cf[cidx];
                        Cf[cidx] = v;
                    }
                }
            }
        }
    }

    if constexpr (LSE) {  // per-(row, 64-col slice) partial logsumexp from acc
        int pcol = by * WN + wc;
#pragma unroll
        for (int m = 0; m < FM; ++m) {
#pragma unroll
            for (int r = 0; r < 4; ++r) {
                float mx = -INFINITY;
#pragma unroll
                for (int n = 0; n < FN; ++n) {
                    int col = n0 + wc * FN * 16 + n * 16 + lr;
                    if (col < Nc) mx = fmaxf(mx, acc[m][n][r]);
                }
                mx = fmaxf(mx, __shfl_xor(mx, 1, 16));
                mx = fmaxf(mx, __shfl_xor(mx, 2, 16));
                mx = fmaxf(mx, __shfl_xor(mx, 4, 16));
                mx = fmaxf(mx, __shfl_xor(mx, 8, 16));
                float s = 0.f;
#pragma unroll
                for (int n = 0; n < FN; ++n) {
                    int col = n0 + wc * FN * 16 + n * 16 + lr;
                    if (col < Nc) s += __expf(acc[m][n][r] - mx);
                }
                s += __shfl_xor(s, 1, 16); s += __shfl_xor(s, 2, 16);
                s += __shfl_xor(s, 4, 16); s += __shfl_xor(s, 8, 16);
                if (lr == 0) {
                    int row = m0 + wr * FM * 16 + m * 16 + lk * 4 + r;
                    lsePart[(long)row * NPART + pcol] = make_float2(mx, s);
                }
            }
        }
    }
}

// ---------------------------------------------------------------- causal softmax, one pass in registers
__global__ __launch_bounds__(256) void att_softmax(__hip_bfloat16* __restrict__ P) {
    int q = blockIdx.x, z = blockIdx.y;
    __hip_bfloat16* row = P + (long)z * (TSEQ * TSEQ) + (long)q * TSEQ;
    int len = q + 1;
    int tid = threadIdx.x;
    short4 v = *(const short4*)&row[tid * 4];
    float x[4];
#pragma unroll
    for (int j = 0; j < 4; ++j) {
        int k = tid * 4 + j;
        short sv = (&v.x)[j];
        x[j] = (k < len) ? bf2f(sv) : -INFINITY;
    }
    __shared__ float red[8];
    float m = fmaxf(fmaxf(x[0], x[1]), fmaxf(x[2], x[3]));
    for (int o = 32; o; o >>= 1) m = fmaxf(m, __shfl_xor(m, o));
    if ((tid & 63) == 0) red[tid >> 6] = m;
    __syncthreads();
    m = fmaxf(fmaxf(red[0], red[1]), fmaxf(red[2], red[3]));
    float e[4];
    float s = 0.f;
#pragma unroll
    for (int j = 0; j < 4; ++j) {
        e[j] = (x[j] == -INFINITY) ? 0.f : __expf(x[j] - m);
        s += e[j];
    }
    for (int o = 32; o; o >>= 1) s += __shfl_xor(s, o);
    if ((tid & 63) == 0) red[4 + (tid >> 6)] = s;
    __syncthreads();
    s = red[4] + red[5] + red[6] + red[7];
    float inv = 1.f / s;
    alignas(8) __hip_bfloat16 t[4];
#pragma unroll
    for (int j = 0; j < 4; ++j) t[j] = __float2bfloat16(e[j] * inv);
    *(short4*)&row[tid * 4] = *(short4*)t;
}

// ---------------------------------------------------------------- V transpose: vT[z][64][1024]
__global__ __launch_bounds__(256) void vtrans(const __hip_bfloat16* __restrict__ qkv,
                                              __hip_bfloat16* __restrict__ vT) {
    int z = blockIdx.y; int b = z >> 3, h = z & 7;
    int k0 = blockIdx.x * 64;
    __shared__ __hip_bfloat16 t[64 * 65];
    int tid = threadIdx.x;
#pragma unroll
    for (int i = 0; i < 16; ++i) {
        int lin = i * 256 + tid;
        int k = lin >> 6, n = lin & 63;
        t[k * 65 + n] =
            qkv[(long)(b * TSEQ + k0 + k) * 1536 + 1024 + h * 64 + n];
    }
    __syncthreads();
#pragma unroll
    for (int i = 0; i < 16; ++i) {
        int lin = i * 256 + tid;
        int n = lin >> 6, k = lin & 63;
        vT[(long)z * (64 * TSEQ) + (long)n * TSEQ + k0 + k] = t[k * 65 + n];
    }
}

// ---------------------------------------------------------------- merge per-row LSE partials -> nll
__global__ __launch_bounds__(256) void nll_part(const float2* __restrict__ part,
                                                const float* __restrict__ logits,
                                                const int* __restrict__ tgt,
                                                float* __restrict__ nll) {
    int row = blockIdx.x;
    const float2* p = part + (long)row * NPART;
    __shared__ float sm[4], ss[4];
    float m = -INFINITY, s = 0.f;
    for (int i = threadIdx.x; i < NPART; i += 256) {
        float2 v = p[i];
        float M = fmaxf(m, v.x);
        s = s * __expf(m - M) + v.y * __expf(v.x - M);
        m = M;
    }
    for (int o = 32; o; o >>= 1) {
        float om = __shfl_xor(m, o), os = __shfl_xor(s, o);
        float M = fmaxf(m, om);
        s = s * __expf(m - M) + os * __expf(om - M);
        m = M;
    }
    if ((threadIdx.x & 63) == 0) { sm[threadIdx.x >> 6] = m; ss[threadIdx.x >> 6] = s; }
    __syncthreads();
    if (threadIdx.x == 0) {
        float M = fmaxf(fmaxf(sm[0], sm[1]), fmaxf(sm[2], sm[3]));
        float S = ss[0] * expf(sm[0] - M) + ss[1] * expf(sm[1] - M) +
                  ss[2] * expf(sm[2] - M) + ss[3] * expf(sm[3] - M);
        nll[row] = M + logf(S) - logits[(long)row * NVOC + tgt[row]];
    }
}

__global__ __launch_bounds__(256) void loss_final(const float* __restrict__ nll,
                                                  float* __restrict__ out) {
    __shared__ float red[4];
    float s = 0.f;
    for (int i = threadIdx.x; i < NTOK; i += 256) s += nll[i];
    for (int o = 32; o; o >>= 1) s += __shfl_xor(s, o);
    if ((threadIdx.x & 63) == 0) red[threadIdx.x >> 6] = s;
    __syncthreads();
    if (threadIdx.x == 0)
        out[0] = (red[0] + red[1] + red[2] + red[3]) * (1.f / NTOK);
}

// ---------------------------------------------------------------- launch
extern "C" void kernel_launch(void* const* d_in, const int* in_sizes, int n_in,
                              void* d_out, int out_size, void* d_ws, size_t ws_size,
                              hipStream_t stream) {
    (void)in_sizes; (void)n_in; (void)out_size;
    const int*   idx  = (const int*)d_in[0];
    const int*   tgt  = (const int*)d_in[1];
    const float* tok  = (const float*)d_in[2];
    const float* pos  = (const float*)d_in[3];
    const float* ln1w = (const float*)d_in[4];
    const float* ln1b = (const float*)d_in[5];
    const float* attw = (const float*)d_in[6];
    const float* attb = (const float*)d_in[7];
    const float* prjw = (const float*)d_in[8];
    const float* prjb = (const float*)d_in[9];
    const float* ln2w = (const float*)d_in[10];
    const float* ln2b = (const float*)d_in[11];
    const float* fcw  = (const float*)d_in[12];
    const float* fcb  = (const float*)d_in[13];
    const float* fc2w = (const float*)d_in[14];
    const float* fc2b = (const float*)d_in[15];
    const float* lnfw = (const float*)d_in[16];
    const float* lnfb = (const float*)d_in[17];
    float* dof = (float*)d_out;

    char* base = (char*)d_ws;
    long off = 0;
    float* xf = (float*)(base + off);           off += (long)NTOK * DMODEL * 4;
    __hip_bfloat16* hbf  = (__hip_bfloat16*)(base + off); off += (long)NTOK * DMODEL * 2;
    __hip_bfloat16* qkvb = (__hip_bfloat16*)(base + off); off += (long)NTOK * 1536 * 2;
    __hip_bfloat16* Pb   = (__hip_bfloat16*)(base + off); off += 16L * TSEQ * TSEQ * 2;
    __hip_bfloat16* vTb  = (__hip_bfloat16*)(base + off); off += 16L * 64 * TSEQ * 2;
    __hip_bfloat16* ybf  = (__hip_bfloat16*)(base + off); off += (long)NTOK * DMODEL * 2;
    __hip_bfloat16* fc1b = (__hip_bfloat16*)(base + off); off += (long)NTOK * 2048 * 2;
    __hip_bfloat16* wAtt = (__hip_bfloat16*)(base + off); off += 2L * 1536 * 512 * 2;
    __hip_bfloat16* wPrj = (__hip_bfloat16*)(base + off); off += 2L * 512 * 512 * 2;
    __hip_bfloat16* wFc  = (__hip_bfloat16*)(base + off); off += 2L * 2048 * 512 * 2;
    __hip_bfloat16* wFc2 = (__hip_bfloat16*)(base + off); off += 2L * 512 * 2048 * 2;
    __hip_bfloat16* tokB = (__hip_bfloat16*)(base + off); off += (long)VPAD * DMODEL * 2;
    float2* lseP = (float2*)(base + off);       off += (long)NTOK * NPART * 8;
    float* nllb = (float*)(base + off);         off += NTOK * 4;
    if ((size_t)off > ws_size) return;

    {
        long n4;
        n4 = 2L * 1536 * 512 / 4;
        conv_bf16<<<dim3(1536), 256, 0, stream>>>(attw, wAtt, n4, n4);
        n4 = 2L * 512 * 512 / 4;
        conv_bf16<<<dim3(512), 256, 0, stream>>>(prjw, wPrj, n4, n4);
        n4 = 2L * 2048 * 512 / 4;
        conv_bf16<<<dim3(2048), 256, 0, stream>>>(fcw, wFc, n4, n4);
        n4 = 2L * 512 * 2048 / 4;
        conv_bf16<<<dim3(2048), 256, 0, stream>>>(fc2w, wFc2, n4, n4);
        long t4 = (long)VPAD * DMODEL / 4, s4 = (long)NVOC * DMODEL / 4;
        conv_bf16<<<dim3(4096), 256, 0, stream>>>(tok, tokB, t4, s4);
    }

    embed_k<<<dim3(NTOK), 128, 0, stream>>>(idx, tok, pos, xf);

    for (int l = 0; l < 2; ++l) {
        ln_rows<<<dim3(512), 256, 0, stream>>>(xf, ln1w + l * 512, ln1b + l * 512, hbf, NTOK);
        // QKV: [2048,512] x [1536,512]^T -> bf16 + bias   (384 blocks)
        gemm_bt<128, 64, 2, 2, true, true, false, false, false, false>
            <<<dim3(16, 24, 1), 256, 0, stream>>>(
            hbf, 512, 0, 0, wAtt + (long)l * 1536 * 512, 512, 0, 0,
            qkvb, 1536, 0, 0, attb + l * 1536, 512, 1536, 1.f, 1, nullptr);
        // S = Q K^T / 8 (batched z=16)
        gemm_bt<128, 128, 2, 2, true, false, false, false, false, false>
            <<<dim3(8, 8, 16), 256, 0, stream>>>(
            qkvb, 1536, 1536L * TSEQ, 64, qkvb + 512, 1536, 1536L * TSEQ, 64,
            Pb, TSEQ, 8L * TSEQ * TSEQ, (long)TSEQ * TSEQ, nullptr,
            64, TSEQ, 0.125f, 8, nullptr);
        att_softmax<<<dim3(TSEQ, 16), 256, 0, stream>>>(Pb);
        vtrans<<<dim3(16, 16), 256, 0, stream>>>(qkvb, vTb);
        // y = P V  (256 blocks)
        gemm_bt<64, 64, 2, 2, true, false, false, false, false, false>
            <<<dim3(16, 1, 16), 256, 0, stream>>>(
            Pb, TSEQ, 8L * TSEQ * TSEQ, (long)TSEQ * TSEQ,
            vTb, TSEQ, 8L * 64 * TSEQ, 64L * TSEQ,
            ybf, 512, 512L * TSEQ, 64, nullptr, TSEQ, 64, 1.f, 8, nullptr);
        // x += y W_proj^T + b  (256 blocks)
        gemm_bt<64, 64, 2, 2, false, true, false, true, false, false>
            <<<dim3(32, 8, 1), 256, 0, stream>>>(
            ybf, 512, 0, 0, wPrj + (long)l * 512 * 512, 512, 0, 0,
            xf, 512, 0, 0, prjb + l * 512, 512, 512, 1.f, 1, nullptr);
        ln_rows<<<dim3(512), 256, 0, stream>>>(xf, ln2w + l * 512, ln2b + l * 512, hbf, NTOK);
        // fc1 + gelu  (256 blocks)
        gemm_bt<128, 128, 2, 2, true, true, true, false, false, false>
            <<<dim3(16, 16, 1), 256, 0, stream>>>(
            hbf, 512, 0, 0, wFc + (long)l * 2048 * 512, 512, 0, 0,
            fc1b, 2048, 0, 0, fcb + l * 2048, 512, 2048, 1.f, 1, nullptr);
        // x += fc1 W_fc2^T + b  (256 blocks)
        gemm_bt<64, 64, 2, 2, false, true, false, true, false, false>
            <<<dim3(32, 8, 1), 256, 0, stream>>>(
            fc1b, 2048, 0, 0, wFc2 + (long)l * 512 * 2048, 2048, 0, 0,
            xf, 512, 0, 0, fc2b + l * 512, 2048, 512, 1.f, 1, nullptr);
    }

    ln_rows<<<dim3(512), 256, 0, stream>>>(xf, lnfw, lnfb, hbf, NTOK);
    // logits + fused partial-LSE: 256x128 tile, 8 waves (3144 blocks, swizzled)
    gemm_bt<256, 128, 4, 2, false, false, false, false, true, true>
        <<<dim3(8, 393, 1), 512, 0, stream>>>(
        hbf, 512, 0, 0, tokB, 512, 0, 0,
        dof, NVOC, 0, 0, nullptr, 512, NVOC, 1.f, 1, lseP);

    nll_part<<<dim3(NTOK), 256, 0, stream>>>(lseP, dof, tgt, nllb);
    loss_final<<<dim3(1), 256, 0, stream>>>(nllb, dof + (long)NTOK * NVOC);
}

// Round 8
// 634.415 us; speedup vs baseline: 1.1126x; 1.0137x over previous
//
#include <hip/hip_runtime.h>
#include <hip/hip_bf16.h>
#include <math.h>

// GPT-small fwd: B=2, T=1024, D=512, H=8, HD=64, L=2, V=50257
// bf16 MFMA (16x16x32) for all matmuls, fp32 residual/LN/softmax/loss.

typedef short bf16x8 __attribute__((ext_vector_type(8)));
typedef short short8 __attribute__((ext_vector_type(8)));
typedef float f32x4 __attribute__((ext_vector_type(4)));

#define NTOK   2048
#define DMODEL 512
#define TSEQ   1024
#define NVOC   50257
#define VPAD   50304
#define NPART  1572       // 393 col-tiles * 4 wave-col slices (32 cols each)

// ---------------------------------------------------------------- helpers
__device__ __forceinline__ float gelu_exact(float x) {
    return 0.5f * x * (1.f + erff(x * 0.70710678118654752f));
}
__device__ __forceinline__ float bf2f(short s) {
    unsigned u = ((unsigned)(unsigned short)s) << 16;
    union { unsigned u; float f; } c; c.u = u; return c.f;
}

typedef __attribute__((address_space(1))) const void global_cvoid;
typedef __attribute__((address_space(3))) void lds_void;
__device__ __forceinline__ void glds16(const void* g, void* l) {
    // async global->LDS, 16B/lane; LDS dest = wave-uniform base + lane*16
    __builtin_amdgcn_global_load_lds((global_cvoid*)g, (lds_void*)l, 16, 0, 0);
}
__device__ __forceinline__ void rawbar() {
    asm volatile("" ::: "memory");
    __builtin_amdgcn_s_barrier();
    asm volatile("" ::: "memory");
}

// ---------------------------------------------------------------- f32 -> bf16 (zero-pad past nsrc4)
__global__ __launch_bounds__(256) void conv_bf16(const float* __restrict__ in,
                                                 __hip_bfloat16* __restrict__ out,
                                                 long n4, long nsrc4) {
    for (long i = (long)blockIdx.x * blockDim.x + threadIdx.x; i < n4;
         i += (long)gridDim.x * blockDim.x) {
        float4 v;
        if (i < nsrc4) v = ((const float4*)in)[i];
        else { v.x = v.y = v.z = v.w = 0.f; }
        alignas(8) __hip_bfloat16 t[4];
        t[0] = __float2bfloat16(v.x); t[1] = __float2bfloat16(v.y);
        t[2] = __float2bfloat16(v.z); t[3] = __float2bfloat16(v.w);
        *(uint2*)&out[i * 4] = *(uint2*)t;
    }
}

// ---------------------------------------------------------------- embedding
__global__ __launch_bounds__(128) void embed_k(const int* __restrict__ idx,
                                               const float* __restrict__ tok,
                                               const float* __restrict__ pos,
                                               float* __restrict__ x) {
    int row = blockIdx.x;
    int t = row & (TSEQ - 1);
    int id = idx[row];
    const float4* a = (const float4*)(tok + (long)id * DMODEL);
    const float4* p = (const float4*)(pos + (long)t * DMODEL);
    float4* o = (float4*)(x + (long)row * DMODEL);
    int i = threadIdx.x;
    float4 u = a[i], q = p[i];
    u.x += q.x; u.y += q.y; u.z += q.z; u.w += q.w;
    o[i] = u;
}

// ---------------------------------------------------------------- LayerNorm (wave per row), fp32 -> bf16
__global__ __launch_bounds__(256) void ln_rows(const float* __restrict__ x,
                                               const float* __restrict__ w,
                                               const float* __restrict__ b,
                                               __hip_bfloat16* __restrict__ out,
                                               int nrows) {
    int wv = threadIdx.x >> 6, l = threadIdx.x & 63;
    int row = blockIdx.x * 4 + wv;
    if (row >= nrows) return;
    const float4* xr = (const float4*)(x + (long)row * DMODEL);
    float4 v0 = xr[l * 2], v1 = xr[l * 2 + 1];
    float s = v0.x + v0.y + v0.z + v0.w + v1.x + v1.y + v1.z + v1.w;
    for (int o = 32; o; o >>= 1) s += __shfl_xor(s, o);
    float mu = s * (1.f / DMODEL);
    float d, q = 0.f;
    d = v0.x - mu; q += d * d; d = v0.y - mu; q += d * d;
    d = v0.z - mu; q += d * d; d = v0.w - mu; q += d * d;
    d = v1.x - mu; q += d * d; d = v1.y - mu; q += d * d;
    d = v1.z - mu; q += d * d; d = v1.w - mu; q += d * d;
    for (int o = 32; o; o >>= 1) q += __shfl_xor(q, o);
    float rs = rsqrtf(q * (1.f / DMODEL) + 1e-5f);
    const float4* wr = (const float4*)w; const float4* br = (const float4*)b;
    float4 w0 = wr[l * 2], w1 = wr[l * 2 + 1], b0 = br[l * 2], b1 = br[l * 2 + 1];
    alignas(16) __hip_bfloat16 t[8];
    t[0] = __float2bfloat16((v0.x - mu) * rs * w0.x + b0.x);
    t[1] = __float2bfloat16((v0.y - mu) * rs * w0.y + b0.y);
    t[2] = __float2bfloat16((v0.z - mu) * rs * w0.z + b0.z);
    t[3] = __float2bfloat16((v0.w - mu) * rs * w0.w + b0.w);
    t[4] = __float2bfloat16((v1.x - mu) * rs * w1.x + b1.x);
    t[5] = __float2bfloat16((v1.y - mu) * rs * w1.y + b1.y);
    t[6] = __float2bfloat16((v1.z - mu) * rs * w1.z + b1.z);
    t[7] = __float2bfloat16((v1.w - mu) * rs * w1.w + b1.w);
    *(int4*)&out[(long)row * DMODEL + l * 8] = *(int4*)t;
}

// ---------------------------------------------------------------- head GEMM (phase-interleaved, T3+T4):
// C[2048 x 50257] = A[2048x512] * B[VPADx512]^T, fp32 out + LSE partials.
// BM=128 BN=128 BK=64, 8 waves (2Mx4N), dbuf 64KB LDS (2 blocks/CU).
// Per K-tile: [bar; stageA(t+1); vmcnt(2); bar] then 4 phases
// {4 ds_read + 4 MFMA}, stageB(t+1) interleaved after phase 0.
// Chunk = 16 rows x 32 k, lane l -> (row=l&15, k=(l>>4)*8): conflict-free.
__global__ __launch_bounds__(512) void gemm_head(
    const __hip_bfloat16* __restrict__ A,      // lda 512
    const __hip_bfloat16* __restrict__ B,      // ldb 512, VPAD rows
    float* __restrict__ C,                     // ldc NVOC
    float2* __restrict__ lsePart, int K) {
    __shared__ __align__(16) __hip_bfloat16 L[2][16384];  // [buf][A:16ch | B:16ch] 64KB
    const int tid = threadIdx.x;
    const int l = tid & 63, w = tid >> 6;
    const int wr = w >> 2, wc = w & 3;     // 2 x 4 waves
    // bijective chunked XCD swizzle (6288 % 8 == 0)
    int lin = blockIdx.y * gridDim.x + blockIdx.x;
    int q = (gridDim.x * gridDim.y) >> 3;
    int nl = (lin & 7) * q + (lin >> 3);
    int bx = nl % gridDim.x, by = nl / gridDim.x;
    const int m0 = bx * 128, n0 = by * 128;
    const int lr = l & 15, lk = l >> 4;

    // staging source pointers (2 A-chunks + 2 B-chunks per wave), +64 per tile
    const __hip_bfloat16* pA[2];
    const __hip_bfloat16* pB[2];
#pragma unroll
    for (int i = 0; i < 2; ++i) {
        int c = w * 2 + i;                 // chunk 0..15
        pA[i] = A + (long)(m0 + (c >> 1) * 16 + lr) * 512 + (c & 1) * 32 + lk * 8;
        pB[i] = B + (long)(n0 + (c >> 1) * 16 + lr) * 512 + (c & 1) * 32 + lk * 8;
    }

    f32x4 acc[4][2];
#pragma unroll
    for (int m = 0; m < 4; ++m)
#pragma unroll
        for (int n = 0; n < 2; ++n)
            for (int r = 0; r < 4; ++r) acc[m][n][r] = 0.f;

    auto stageA = [&](int d) {
#pragma unroll
        for (int i = 0; i < 2; ++i) {
            glds16(pA[i], &L[d][(w * 2 + i) * 512]);
            pA[i] += 64;
        }
    };
    auto stageB = [&](int d) {
#pragma unroll
        for (int i = 0; i < 2; ++i) {
            glds16(pB[i], &L[d][8192 + (w * 2 + i) * 512]);
            pB[i] += 64;
        }
    };
    // one phase: (mh, kk): 2 A-frags + 2 B-frags, 4 MFMA
    auto phase = [&](int d, int mh, int kk) {
        bf16x8 aF[2], bF[2];
#pragma unroll
        for (int j = 0; j < 2; ++j)
            aF[j] = *(const bf16x8*)&L[d][((wr * 4 + mh * 2 + j) * 2 + kk) * 512 + l * 8];
#pragma unroll
        for (int n = 0; n < 2; ++n)
            bF[n] = *(const bf16x8*)&L[d][8192 + ((wc * 2 + n) * 2 + kk) * 512 + l * 8];
        __builtin_amdgcn_s_setprio(1);
#pragma unroll
        for (int j = 0; j < 2; ++j)
#pragma unroll
            for (int n = 0; n < 2; ++n)
                acc[mh * 2 + j][n] = __builtin_amdgcn_mfma_f32_16x16x32_bf16(
                    aF[j], bF[n], acc[mh * 2 + j][n], 0, 0, 0);
        __builtin_amdgcn_s_setprio(0);
    };

    const int nt = K / 64;    // 8
    stageA(0); stageB(0);
    int d = 0;
    for (int t = 0; t < nt - 1; ++t) {
        rawbar();                       // all reads of buf[d^1] (tile t-1) done
        stageA(d ^ 1);                  // tile t+1 (2 glds)
        asm volatile("s_waitcnt vmcnt(2)" ::: "memory");  // tile t landed
        rawbar();                       // cross-wave visibility
        phase(d, 0, 0);
        stageB(d ^ 1);                  // tile t+1 (2 glds)
        phase(d, 0, 1);
        phase(d, 1, 0);
        phase(d, 1, 1);
        d ^= 1;
    }
    // tail tile
    rawbar();
    asm volatile("s_waitcnt vmcnt(0)" ::: "memory");
    rawbar();
    phase(d, 0, 0);
    phase(d, 0, 1);
    phase(d, 1, 0);
    phase(d, 1, 1);

    // epilogue: acc -> LDS bounce (16KB, reuse L) -> coalesced float4 stores
    rawbar();
    float* ep = (float*)&L[0][0];
#pragma unroll
    for (int mi = 0; mi < 4; ++mi) {
#pragma unroll
        for (int n = 0; n < 2; ++n) {
            int cb = wc * 32 + n * 16 + lr;
#pragma unroll
            for (int r = 0; r < 4; ++r)
                ep[(wr * 16 + lk * 4 + r) * 128 + cb] = acc[mi][n][r];
        }
        __syncthreads();
#pragma unroll
        for (int i = 0; i < 2; ++i) {
            int flat = (i * 512 + tid) * 4;
            int s = flat >> 11;              // /2048
            int rr = (flat & 2047) >> 7;     // /128
            int c = flat & 127;
            long grow = m0 + s * 64 + mi * 16 + rr;
            int gcol = n0 + c;
            if (gcol + 4 <= NVOC) {
                *(float4*)(C + grow * NVOC + gcol) = *(const float4*)(ep + flat);
            } else {
#pragma unroll
                for (int e = 0; e < 4; ++e)
                    if (gcol + e < NVOC) C[grow * NVOC + gcol + e] = ep[flat + e];
            }
        }
        __syncthreads();
    }

    // LSE partials: per (row, 32-col wave slice)
    int pcol = by * 4 + wc;
#pragma unroll
    for (int f = 0; f < 4; ++f) {
#pragma unroll
        for (int r = 0; r < 4; ++r) {
            float mx = -INFINITY;
#pragma unroll
            for (int n = 0; n < 2; ++n) {
                int col = n0 + wc * 32 + n * 16 + lr;
                if (col < NVOC) mx = fmaxf(mx, acc[f][n][r]);
            }
            mx = fmaxf(mx, __shfl_xor(mx, 1, 16));
            mx = fmaxf(mx, __shfl_xor(mx, 2, 16));
            mx = fmaxf(mx, __shfl_xor(mx, 4, 16));
            mx = fmaxf(mx, __shfl_xor(mx, 8, 16));
            float s = 0.f;
#pragma unroll
            for (int n = 0; n < 2; ++n) {
                int col = n0 + wc * 32 + n * 16 + lr;
                if (col < NVOC) s += __expf(acc[f][n][r] - mx);
            }
            s += __shfl_xor(s, 1, 16); s += __shfl_xor(s, 2, 16);
            s += __shfl_xor(s, 4, 16); s += __shfl_xor(s, 8, 16);
            if (lr == 0) {
                int row = m0 + wr * 64 + f * 16 + lk * 4 + r;
                lsePart[(long)row * NPART + pcol] = make_float2(mx, s);
            }
        }
    }
}

// ---------------------------------------------------------------- GEMM: C = alpha * A(MxK) * B(NxK)^T [+bias][gelu][+resid]
// (r6 structure: counted-vmcnt dbuf + LDS-bounce epilogue; used for layer GEMMs)
template<int BM, int BN, int WM, int WN, bool OBF16, bool BIAS, bool GELUF,
         bool RESID>
__global__ __launch_bounds__(WM * WN * 64) void gemm_bt(
    const __hip_bfloat16* __restrict__ A, int lda, long sAhi, long sAlo,
    const __hip_bfloat16* __restrict__ B, int ldb, long sBhi, long sBlo,
    void* __restrict__ Cp, long ldc, long sChi, long sClo,
    const float* __restrict__ bias,
    int K, int Nc, float alpha, int zdiv) {
    constexpr int NW = WM * WN, NT = NW * 64;
    constexpr int FM = BM / (WM * 16), FN = BN / (WN * 16);
    constexpr int CAW = (BM / 16) / NW, CBW = (BN / 16) / NW;
    constexpr int NL = CAW + CBW;
    static_assert(CAW >= 1 && CBW >= 1 && (BM / 16) % NW == 0 &&
                  (BN / 16) % NW == 0, "chunk split");
    constexpr int STG = (BM + BN) * 32;
    constexpr int EPB = WM * 16 * BN * 4;
    constexpr int SMB = (2 * STG * 2 > EPB) ? 2 * STG * 2 : EPB;
    __shared__ __align__(16) char smem[SMB];
    __hip_bfloat16* st0 = (__hip_bfloat16*)smem;
    __hip_bfloat16* st1 = st0 + STG;
    const int tid = threadIdx.x;
    const int l = tid & 63, w = tid >> 6;
    const int wr = w / WN, wc = w % WN;
    int bx = blockIdx.x, by = blockIdx.y;
    const int z = blockIdx.z;
    const int zh = z / zdiv, zl = z % zdiv;
    const __hip_bfloat16* Az = A + (long)zh * sAhi + (long)zl * sAlo;
    const __hip_bfloat16* Bz = B + (long)zh * sBhi + (long)zl * sBlo;
    const long Coff = (long)zh * sChi + (long)zl * sClo;
    const int m0 = bx * BM, n0 = by * BN;
    const int lr = l & 15, lk = l >> 4;

    const __hip_bfloat16* pA[CAW];
    const __hip_bfloat16* pB[CBW];
#pragma unroll
    for (int i = 0; i < CAW; ++i)
        pA[i] = Az + (long)(m0 + (w * CAW + i) * 16 + lr) * lda + lk * 8;
#pragma unroll
    for (int i = 0; i < CBW; ++i)
        pB[i] = Bz + (long)(n0 + (w * CBW + i) * 16 + lr) * ldb + lk * 8;

    f32x4 acc[FM][FN];
#pragma unroll
    for (int m = 0; m < FM; ++m)
#pragma unroll
        for (int n = 0; n < FN; ++n)
            for (int r = 0; r < 4; ++r) acc[m][n][r] = 0.f;

    auto stage = [&](__hip_bfloat16* buf) {
#pragma unroll
        for (int i = 0; i < CAW; ++i) {
            glds16(pA[i], buf + (w * CAW + i) * 512);
            pA[i] += 32;
        }
#pragma unroll
        for (int i = 0; i < CBW; ++i) {
            glds16(pB[i], buf + BM * 32 + (w * CBW + i) * 512);
            pB[i] += 32;
        }
    };
    auto compute = [&](const __hip_bfloat16* buf) {
        const __hip_bfloat16* bA = buf;
        const __hip_bfloat16* bB = buf + BM * 32;
        bf16x8 af[FM], bv[FN];
#pragma unroll
        for (int m = 0; m < FM; ++m)
            af[m] = *(const bf16x8*)&bA[(wr * FM + m) * 512 + l * 8];
#pragma unroll
        for (int n = 0; n < FN; ++n)
            bv[n] = *(const bf16x8*)&bB[(wc * FN + n) * 512 + l * 8];
        __builtin_amdgcn_s_setprio(1);
#pragma unroll
        for (int m = 0; m < FM; ++m)
#pragma unroll
            for (int n = 0; n < FN; ++n)
                acc[m][n] = __builtin_amdgcn_mfma_f32_16x16x32_bf16(
                    af[m], bv[n], acc[m][n], 0, 0, 0);
        __builtin_amdgcn_s_setprio(0);
    };

    const int nt = K / 32;
    stage(st0);
    int t = 0;
    for (; t + 2 <= nt - 1; t += 2) {
        stage(st1);
        asm volatile("s_waitcnt vmcnt(%0)" :: "n"(NL) : "memory");
        rawbar();
        compute(st0);
        rawbar();
        stage(st0);
        asm volatile("s_waitcnt vmcnt(%0)" :: "n"(NL) : "memory");
        rawbar();
        compute(st1);
        rawbar();
    }
    if (t < nt - 1) {
        stage(st1);
        asm volatile("s_waitcnt vmcnt(%0)" :: "n"(NL) : "memory");
        rawbar();
        compute(st0);
        rawbar();
        asm volatile("s_waitcnt vmcnt(0)" ::: "memory");
        rawbar();
        compute(st1);
    } else {
        asm volatile("s_waitcnt vmcnt(0)" ::: "memory");
        rawbar();
        compute(st0);
    }

    __syncthreads();

    if constexpr (!RESID) {
        constexpr int EROW = 16 * BN;
        if constexpr (OBF16) {
            __hip_bfloat16* ep = (__hip_bfloat16*)smem;
            constexpr int VE = (WM * EROW) / (NT * 8);
#pragma unroll
            for (int mi = 0; mi < FM; ++mi) {
#pragma unroll
                for (int n = 0; n < FN; ++n) {
                    int cb = wc * FN * 16 + n * 16 + lr;
#pragma unroll
                    for (int r = 0; r < 4; ++r) {
                        float v = acc[mi][n][r] * alpha;
                        if (BIAS) v += bias[n0 + cb];
                        if (GELUF) v = gelu_exact(v);
                        ep[(wr * 16 + lk * 4 + r) * BN + cb] = __float2bfloat16(v);
                    }
                }
                __syncthreads();
#pragma unroll
                for (int i = 0; i < VE; ++i) {
                    int flat = (i * NT + tid) * 8;
                    int s = flat / EROW;
                    int rr = (flat % EROW) / BN;
                    int c = flat % BN;
                    long grow = m0 + s * FM * 16 + mi * 16 + rr;
                    *(short8*)((__hip_bfloat16*)Cp + Coff + grow * ldc + n0 + c) =
                        *(const short8*)(ep + flat);
                }
                __syncthreads();
            }
        } else {
            float* ep = (float*)smem;
            float* Cf = (float*)Cp;
            constexpr int VE = (WM * EROW) / (NT * 4);
#pragma unroll
            for (int mi = 0; mi < FM; ++mi) {
#pragma unroll
                for (int n = 0; n < FN; ++n) {
                    int cb = wc * FN * 16 + n * 16 + lr;
#pragma unroll
                    for (int r = 0; r < 4; ++r) {
                        float v = acc[mi][n][r] * alpha;
                        if (BIAS) v += bias[n0 + cb];
                        if (GELUF) v = gelu_exact(v);
                        ep[(wr * 16 + lk * 4 + r) * BN + cb] = v;
                    }
                }
                __syncthreads();
#pragma unroll
                for (int i = 0; i < VE; ++i) {
                    int flat = (i * NT + tid) * 4;
                    int s = flat / EROW;
                    int rr = (flat % EROW) / BN;
                    int c = flat % BN;
                    long grow = m0 + s * FM * 16 + mi * 16 + rr;
                    int gcol = n0 + c;
                    if (gcol + 4 <= Nc) {
                        *(float4*)(Cf + Coff + grow * ldc + gcol) =
                            *(const float4*)(ep + flat);
                    } else {
#pragma unroll
                        for (int e = 0; e < 4; ++e)
                            if (gcol + e < Nc)
                                Cf[Coff + grow * ldc + gcol + e] = ep[flat + e];
                    }
                }
                __syncthreads();
            }
        }
    } else {
#pragma unroll
        for (int m = 0; m < FM; ++m) {
            int rowb = m0 + wr * FM * 16 + m * 16 + lk * 4;
#pragma unroll
            for (int n = 0; n < FN; ++n) {
                int col = n0 + wc * FN * 16 + n * 16 + lr;
                if (col < Nc) {
#pragma unroll
                    for (int r = 0; r < 4; ++r) {
                        float v = acc[m][n][r] * alpha;
                        if (BIAS) v += bias[col];
                        if (GELUF) v = gelu_exact(v);
                        long cidx = Coff + (long)(rowb + r) * ldc + col;
                        float* Cf = (float*)Cp;
                        v += Cf[cidx];
                        Cf[cidx] = v;
                    }
                }
            }
        }
    }
}

// ---------------------------------------------------------------- causal softmax, one pass in registers
__global__ __launch_bounds__(256) void att_softmax(__hip_bfloat16* __restrict__ P) {
    int q = blockIdx.x, z = blockIdx.y;
    __hip_bfloat16* row = P + (long)z * (TSEQ * TSEQ) + (long)q * TSEQ;
    int len = q + 1;
    int tid = threadIdx.x;
    short4 v = *(const short4*)&row[tid * 4];
    float x[4];
#pragma unroll
    for (int j = 0; j < 4; ++j) {
        int k = tid * 4 + j;
        short sv = (&v.x)[j];
        x[j] = (k < len) ? bf2f(sv) : -INFINITY;
    }
    __shared__ float red[8];
    float m = fmaxf(fmaxf(x[0], x[1]), fmaxf(x[2], x[3]));
    for (int o = 32; o; o >>= 1) m = fmaxf(m, __shfl_xor(m, o));
    if ((tid & 63) == 0) red[tid >> 6] = m;
    __syncthreads();
    m = fmaxf(fmaxf(red[0], red[1]), fmaxf(red[2], red[3]));
    float e[4];
    float s = 0.f;
#pragma unroll
    for (int j = 0; j < 4; ++j) {
        e[j] = (x[j] == -INFINITY) ? 0.f : __expf(x[j] - m);
        s += e[j];
    }
    for (int o = 32; o; o >>= 1) s += __shfl_xor(s, o);
    if ((tid & 63) == 0) red[4 + (tid >> 6)] = s;
    __syncthreads();
    s = red[4] + red[5] + red[6] + red[7];
    float inv = 1.f / s;
    alignas(8) __hip_bfloat16 t[4];
#pragma unroll
    for (int j = 0; j < 4; ++j) t[j] = __float2bfloat16(e[j] * inv);
    *(short4*)&row[tid * 4] = *(short4*)t;
}

// ---------------------------------------------------------------- V transpose: vT[z][64][1024]
__global__ __launch_bounds__(256) void vtrans(const __hip_bfloat16* __restrict__ qkv,
                                              __hip_bfloat16* __restrict__ vT) {
    int z = blockIdx.y; int b = z >> 3, h = z & 7;
    int k0 = blockIdx.x * 64;
    __shared__ __hip_bfloat16 t[64 * 65];
    int tid = threadIdx.x;
#pragma unroll
    for (int i = 0; i < 16; ++i) {
        int lin = i * 256 + tid;
        int k = lin >> 6, n = lin & 63;
        t[k * 65 + n] =
            qkv[(long)(b * TSEQ + k0 + k) * 1536 + 1024 + h * 64 + n];
    }
    __syncthreads();
#pragma unroll
    for (int i = 0; i < 16; ++i) {
        int lin = i * 256 + tid;
        int n = lin >> 6, k = lin & 63;
        vT[(long)z * (64 * TSEQ) + (long)n * TSEQ + k0 + k] = t[k * 65 + n];
    }
}

// ---------------------------------------------------------------- merge per-row LSE partials -> nll
__global__ __launch_bounds__(256) void nll_part(const float2* __restrict__ part,
                                                const float* __restrict__ logits,
                                                const int* __restrict__ tgt,
                                                float* __restrict__ nll) {
    int row = blockIdx.x;
    const float2* p = part + (long)row * NPART;
    __shared__ float sm[4], ss[4];
    float m = -INFINITY, s = 0.f;
    for (int i = threadIdx.x; i < NPART; i += 256) {
        float2 v = p[i];
        float M = fmaxf(m, v.x);
        s = s * __expf(m - M) + v.y * __expf(v.x - M);
        m = M;
    }
    for (int o = 32; o; o >>= 1) {
        float om = __shfl_xor(m, o), os = __shfl_xor(s, o);
        float M = fmaxf(m, om);
        s = s * __expf(m - M) + os * __expf(om - M);
        m = M;
    }
    if ((threadIdx.x & 63) == 0) { sm[threadIdx.x >> 6] = m; ss[threadIdx.x >> 6] = s; }
    __syncthreads();
    if (threadIdx.x == 0) {
        float M = fmaxf(fmaxf(sm[0], sm[1]), fmaxf(sm[2], sm[3]));
        float S = ss[0] * expf(sm[0] - M) + ss[1] * expf(sm[1] - M) +
                  ss[2] * expf(sm[2] - M) + ss[3] * expf(sm[3] - M);
        nll[row] = M + logf(S) - logits[(long)row * NVOC + tgt[row]];
    }
}

__global__ __launch_bounds__(256) void loss_final(const float* __restrict__ nll,
                                                  float* __restrict__ out) {
    __shared__ float red[4];
    float s = 0.f;
    for (int i = threadIdx.x; i < NTOK; i += 256) s += nll[i];
    for (int o = 32; o; o >>= 1) s += __shfl_xor(s, o);
    if ((threadIdx.x & 63) == 0) red[threadIdx.x >> 6] = s;
    __syncthreads();
    if (threadIdx.x == 0)
        out[0] = (red[0] + red[1] + red[2] + red[3]) * (1.f / NTOK);
}

// ---------------------------------------------------------------- launch
extern "C" void kernel_launch(void* const* d_in, const int* in_sizes, int n_in,
                              void* d_out, int out_size, void* d_ws, size_t ws_size,
                              hipStream_t stream) {
    (void)in_sizes; (void)n_in; (void)out_size;
    const int*   idx  = (const int*)d_in[0];
    const int*   tgt  = (const int*)d_in[1];
    const float* tok  = (const float*)d_in[2];
    const float* pos  = (const float*)d_in[3];
    const float* ln1w = (const float*)d_in[4];
    const float* ln1b = (const float*)d_in[5];
    const float* attw = (const float*)d_in[6];
    const float* attb = (const float*)d_in[7];
    const float* prjw = (const float*)d_in[8];
    const float* prjb = (const float*)d_in[9];
    const float* ln2w = (const float*)d_in[10];
    const float* ln2b = (const float*)d_in[11];
    const float* fcw  = (const float*)d_in[12];
    const float* fcb  = (const float*)d_in[13];
    const float* fc2w = (const float*)d_in[14];
    const float* fc2b = (const float*)d_in[15];
    const float* lnfw = (const float*)d_in[16];
    const float* lnfb = (const float*)d_in[17];
    float* dof = (float*)d_out;

    char* base = (char*)d_ws;
    long off = 0;
    float* xf = (float*)(base + off);           off += (long)NTOK * DMODEL * 4;
    __hip_bfloat16* hbf  = (__hip_bfloat16*)(base + off); off += (long)NTOK * DMODEL * 2;
    __hip_bfloat16* qkvb = (__hip_bfloat16*)(base + off); off += (long)NTOK * 1536 * 2;
    __hip_bfloat16* Pb   = (__hip_bfloat16*)(base + off); off += 16L * TSEQ * TSEQ * 2;
    __hip_bfloat16* vTb  = (__hip_bfloat16*)(base + off); off += 16L * 64 * TSEQ * 2;
    __hip_bfloat16* ybf  = (__hip_bfloat16*)(base + off); off += (long)NTOK * DMODEL * 2;
    __hip_bfloat16* fc1b = (__hip_bfloat16*)(base + off); off += (long)NTOK * 2048 * 2;
    __hip_bfloat16* wAtt = (__hip_bfloat16*)(base + off); off += 2L * 1536 * 512 * 2;
    __hip_bfloat16* wPrj = (__hip_bfloat16*)(base + off); off += 2L * 512 * 512 * 2;
    __hip_bfloat16* wFc  = (__hip_bfloat16*)(base + off); off += 2L * 2048 * 512 * 2;
    __hip_bfloat16* wFc2 = (__hip_bfloat16*)(base + off); off += 2L * 512 * 2048 * 2;
    __hip_bfloat16* tokB = (__hip_bfloat16*)(base + off); off += (long)VPAD * DMODEL * 2;
    float* nllb = (float*)(base + off);         off += NTOK * 4;
    // lseP aliases Pb (free after the layer loop): 2048*1572*8 = 25.8MB < 32MB
    float2* lseP = (float2*)Pb;
    if ((size_t)off > ws_size) return;

    {
        long n4;
        n4 = 2L * 1536 * 512 / 4;
        conv_bf16<<<dim3(1536), 256, 0, stream>>>(attw, wAtt, n4, n4);
        n4 = 2L * 512 * 512 / 4;
        conv_bf16<<<dim3(512), 256, 0, stream>>>(prjw, wPrj, n4, n4);
        n4 = 2L * 2048 * 512 / 4;
        conv_bf16<<<dim3(2048), 256, 0, stream>>>(fcw, wFc, n4, n4);
        n4 = 2L * 512 * 2048 / 4;
        conv_bf16<<<dim3(2048), 256, 0, stream>>>(fc2w, wFc2, n4, n4);
        long t4 = (long)VPAD * DMODEL / 4, s4 = (long)NVOC * DMODEL / 4;
        conv_bf16<<<dim3(4096), 256, 0, stream>>>(tok, tokB, t4, s4);
    }

    embed_k<<<dim3(NTOK), 128, 0, stream>>>(idx, tok, pos, xf);

    for (int l = 0; l < 2; ++l) {
        ln_rows<<<dim3(512), 256, 0, stream>>>(xf, ln1w + l * 512, ln1b + l * 512, hbf, NTOK);
        // QKV: [2048,512] x [1536,512]^T -> bf16 + bias   (384 blocks)
        gemm_bt<128, 64, 2, 2, true, true, false, false>
            <<<dim3(16, 24, 1), 256, 0, stream>>>(
            hbf, 512, 0, 0, wAtt + (long)l * 1536 * 512, 512, 0, 0,
            qkvb, 1536, 0, 0, attb + l * 1536, 512, 1536, 1.f, 1);
        // S = Q K^T / 8 (batched z=16)
        gemm_bt<128, 128, 2, 2, true, false, false, false>
            <<<dim3(8, 8, 16), 256, 0, stream>>>(
            qkvb, 1536, 1536L * TSEQ, 64, qkvb + 512, 1536, 1536L * TSEQ, 64,
            Pb, TSEQ, 8L * TSEQ * TSEQ, (long)TSEQ * TSEQ, nullptr,
            64, TSEQ, 0.125f, 8);
        att_softmax<<<dim3(TSEQ, 16), 256, 0, stream>>>(Pb);
        vtrans<<<dim3(16, 16), 256, 0, stream>>>(qkvb, vTb);
        // y = P V  (256 blocks)
        gemm_bt<64, 64, 2, 2, true, false, false, false>
            <<<dim3(16, 1, 16), 256, 0, stream>>>(
            Pb, TSEQ, 8L * TSEQ * TSEQ, (long)TSEQ * TSEQ,
            vTb, TSEQ, 8L * 64 * TSEQ, 64L * TSEQ,
            ybf, 512, 512L * TSEQ, 64, nullptr, TSEQ, 64, 1.f, 8);
        // x += y W_proj^T + b  (256 blocks)
        gemm_bt<64, 64, 2, 2, false, true, false, true>
            <<<dim3(32, 8, 1), 256, 0, stream>>>(
            ybf, 512, 0, 0, wPrj + (long)l * 512 * 512, 512, 0, 0,
            xf, 512, 0, 0, prjb + l * 512, 512, 512, 1.f, 1);
        ln_rows<<<dim3(512), 256, 0, stream>>>(xf, ln2w + l * 512, ln2b + l * 512, hbf, NTOK);
        // fc1 + gelu  (256 blocks)
        gemm_bt<128, 128, 2, 2, true, true, true, false>
            <<<dim3(16, 16, 1), 256, 0, stream>>>(
            hbf, 512, 0, 0, wFc + (long)l * 2048 * 512, 512, 0, 0,
            fc1b, 2048, 0, 0, fcb + l * 2048, 512, 2048, 1.f, 1);
        // x += fc1 W_fc2^T + b  (256 blocks)
        gemm_bt<64, 64, 2, 2, false, true, false, true>
            <<<dim3(32, 8, 1), 256, 0, stream>>>(
            fc1b, 2048, 0, 0, wFc2 + (long)l * 512 * 2048, 2048, 0, 0,
            xf, 512, 0, 0, fc2b + l * 512, 2048, 512, 1.f, 1);
    }

    ln_rows<<<dim3(512), 256, 0, stream>>>(xf, lnfw, lnfb, hbf, NTOK);
    // logits + fused partial-LSE: phase-interleaved head (6288 blocks, swizzled)
    gemm_head<<<dim3(16, 393, 1), 512, 0, stream>>>(hbf, tokB, dof, lseP, 512);

    nll_part<<<dim3(NTOK), 256, 0, stream>>>(lseP, dof, tgt, nllb);
    loss_final<<<dim3(1), 256, 0, stream>>>(nllb, dof + (long)NTOK * NVOC);
}